// Round 9
// baseline (246.070 us; speedup 1.0000x reference)
//
#include <hip/hip_runtime.h>

// DAWN_14886356647950: fused gated sparse read-write (B=2,S=1024,D=1024,N=8192,NC=8)
// R8: R7 (best, 190.6us) + swizzled-LDS epilogue repack in k_sc/k_xr/k_out
// (128 scattered 2B stores/thread -> 16 coalesced 16B), k_xr RMW coalesced,
// k_out chunk-per-XCD L2 mapping. GEMM K-loop unchanged (2-phase plateau).

#define MDIM 2048
#define DDIM 1024
#define NDIM 8192

typedef __attribute__((ext_vector_type(8))) __bf16 bf16x8;
typedef __attribute__((ext_vector_type(4))) float f32x4;

static __device__ __forceinline__ unsigned short f2b(float f) {
  unsigned u = __float_as_uint(f);
  u = (u + 0x7FFFu + ((u >> 16) & 1u)) >> 16;  // RTNE
  return (unsigned short)u;
}
static __device__ __forceinline__ float b2f(unsigned short s) {
  return __uint_as_float(((unsigned)s) << 16);
}
static __device__ __forceinline__ unsigned short bmul(unsigned short a, unsigned short b) {
  return f2b(b2f(a) * b2f(b));
}
static __device__ __forceinline__ unsigned bmul2(unsigned eg, unsigned xr) {
  return (unsigned)bmul((unsigned short)(eg & 0xFFFF), (unsigned short)(xr & 0xFFFF)) |
         ((unsigned)bmul((unsigned short)(eg >> 16), (unsigned short)(xr >> 16)) << 16);
}

#define LDSF(off) (*(const bf16x8*)(lds + (off)))
#define MFMA_BF16 __builtin_amdgcn_mfma_f32_16x16x32_bf16

#define GLOAD_LDS(gp, lp)                                                              \
  __builtin_amdgcn_global_load_lds(                                                    \
      (const __attribute__((address_space(1))) unsigned int*)(const void*)(gp),        \
      (__attribute__((address_space(3))) unsigned int*)(void*)(lp), 16, 0, 0)

// Stage one 128x64 half-tile (16KB); LDS dest linear, swizzle via permuted
// per-lane GLOBAL source column (involution with read-side XOR).
static __device__ __forceinline__ void stage_half(const unsigned short* __restrict__ src,
                                                  int ld, int row0, int k0,
                                                  char* lds, int lds_off, int w, int l) {
  const int rsub = l >> 3;
  const int col = k0 + 8 * ((l & 7) ^ rsub);
#pragma unroll
  for (int j = 0; j < 2; ++j) {
    const unsigned short* g =
        src + (size_t)(row0 + w * 8 + j * 64 + rsub) * (size_t)ld + col;
    GLOAD_LDS(g, lds + lds_off + j * 8192 + w * 1024);
  }
}

static __device__ __forceinline__ void stage4(const unsigned short* __restrict__ asrc,
                                              const unsigned short* __restrict__ bsrc,
                                              int ld, int m0, int n0, int k0,
                                              char* lds, int buf, int w, int l) {
  stage_half(asrc, ld, m0,       k0, lds, buf,         w, l);
  stage_half(asrc, ld, m0 + 128, k0, lds, buf + 16384, w, l);
  stage_half(bsrc, ld, n0,       k0, lds, buf + 32768, w, l);
  stage_half(bsrc, ld, n0 + 128, k0, lds, buf + 49152, w, l);
}

// 256x256 x K=1024 (16 tiles) NT-GEMM, 8 waves (2M x 4N), per-wave 128x64.
static __device__ __forceinline__ void gemm256(const unsigned short* __restrict__ asrc,
                                               const unsigned short* __restrict__ bsrc,
                                               int ld, int m0, int n0, int kbase,
                                               char* lds, f32x4 (&acc)[8][4],
                                               int w, int l, int wr, int wc) {
  const int lrow = l & 15, lk = l >> 4;
  const int axor = (l & 7) << 4;
  const int kx0 = (lk << 4) ^ axor;
  const int kx1 = (64 | (lk << 4)) ^ axor;
  const int arow_off = lrow * 128;
  const int brow_off = ((wc & 1) * 64 + lrow) * 128;

  stage4(asrc, bsrc, ld, m0, n0, kbase, lds, 0, w, l);
  asm volatile("s_waitcnt vmcnt(0)" ::: "memory");
  __builtin_amdgcn_s_barrier();

#pragma unroll 1
  for (int t = 0; t < 16; ++t) {
    const int buf = (t & 1) * 65536;
    const int nbuf = 65536 - buf;
    if (t < 15) stage4(asrc, bsrc, ld, m0, n0, kbase + (t + 1) * 64, lds, nbuf, w, l);

    const int ab = buf + wr * 16384;
    const int bb = buf + 32768 + (wc >> 1) * 16384;
    bf16x8 aLO[4][2], aHI[4][2], bLO[2][2], bHI[2][2];
#pragma unroll
    for (int m = 0; m < 4; ++m) {
      aLO[m][0] = LDSF(ab + arow_off + m * 2048 + kx0);
      aLO[m][1] = LDSF(ab + arow_off + m * 2048 + kx1);
    }
#pragma unroll
    for (int n = 0; n < 2; ++n) {
      bLO[n][0] = LDSF(bb + brow_off + n * 2048 + kx0);
      bLO[n][1] = LDSF(bb + brow_off + n * 2048 + kx1);
      bHI[n][0] = LDSF(bb + brow_off + (n + 2) * 2048 + kx0);
      bHI[n][1] = LDSF(bb + brow_off + (n + 2) * 2048 + kx1);
    }
    asm volatile("s_waitcnt lgkmcnt(0)" ::: "memory");
    __builtin_amdgcn_s_setprio(1);
#pragma unroll
    for (int ks = 0; ks < 2; ++ks)
#pragma unroll
      for (int n = 0; n < 2; ++n)
#pragma unroll
        for (int m = 0; m < 4; ++m)
          acc[m][n] = MFMA_BF16(aLO[m][ks], bLO[n][ks], acc[m][n], 0, 0, 0);
    __builtin_amdgcn_s_setprio(0);
#pragma unroll
    for (int m = 0; m < 4; ++m) {
      aHI[m][0] = LDSF(ab + arow_off + (m + 4) * 2048 + kx0);
      aHI[m][1] = LDSF(ab + arow_off + (m + 4) * 2048 + kx1);
    }
    __builtin_amdgcn_s_setprio(1);
#pragma unroll
    for (int ks = 0; ks < 2; ++ks)
#pragma unroll
      for (int n = 0; n < 2; ++n)
#pragma unroll
        for (int m = 0; m < 4; ++m)
          acc[m][n + 2] = MFMA_BF16(aLO[m][ks], bHI[n][ks], acc[m][n + 2], 0, 0, 0);
    __builtin_amdgcn_s_setprio(0);
    asm volatile("s_waitcnt lgkmcnt(0)" ::: "memory");
    __builtin_amdgcn_s_setprio(1);
#pragma unroll
    for (int ks = 0; ks < 2; ++ks)
#pragma unroll
      for (int n = 0; n < 2; ++n)
#pragma unroll
        for (int m = 0; m < 4; ++m)
          acc[m + 4][n + 2] = MFMA_BF16(aHI[m][ks], bHI[n][ks], acc[m + 4][n + 2], 0, 0, 0);
#pragma unroll
    for (int ks = 0; ks < 2; ++ks)
#pragma unroll
      for (int n = 0; n < 2; ++n)
#pragma unroll
        for (int m = 0; m < 4; ++m)
          acc[m + 4][n] = MFMA_BF16(aHI[m][ks], bLO[n][ks], acc[m + 4][n], 0, 0, 0);
    __builtin_amdgcn_s_setprio(0);
    asm volatile("s_waitcnt vmcnt(0)" ::: "memory");
    __builtin_amdgcn_s_barrier();
  }
}

// Epilogue repack swizzle: value (row rl, col cl) at byte rl*512 + (2*cl ^ sw(rl)),
// sw(rl) = ((rl>>2)&3)<<5 -> conflict-free ds_write_b16; 16B chunks stay intact.
#define SWR(r) ((((r) >> 2) & 3) << 5)

// ==================== fused prep (single dispatch) ====================

__global__ __launch_bounds__(256) void k_prep(const float* __restrict__ emb,
                                              const float* __restrict__ w_read,
                                              const float* __restrict__ h,
                                              const float* __restrict__ x,
                                              const float* __restrict__ w_write,
                                              unsigned short* __restrict__ eb,
                                              unsigned short* __restrict__ rb,
                                              unsigned short* __restrict__ hb,
                                              unsigned short* __restrict__ xb,
                                              unsigned short* __restrict__ wbT) {
  const int b = blockIdx.x, t = threadIdx.x;
  if (b < 2048) {  // w_write transpose
    __shared__ float tsm[64][65];
    const int nb = b & 127, db = b >> 7;
    const int r = t >> 2, c4 = (t & 3) * 16;
#pragma unroll
    for (int j = 0; j < 4; ++j) {
      const float4 v = *(const float4*)&w_write[(size_t)(nb * 64 + r) * 1024 + db * 64 + c4 + 4 * j];
      tsm[r][c4 + 4 * j + 0] = v.x;
      tsm[r][c4 + 4 * j + 1] = v.y;
      tsm[r][c4 + 4 * j + 2] = v.z;
      tsm[r][c4 + 4 * j + 3] = v.w;
    }
    __syncthreads();
    const int dr = t >> 2, nc0 = (t & 3) * 16;
    unsigned pk[8];
#pragma unroll
    for (int j = 0; j < 8; ++j) {
      const unsigned lo = f2b(tsm[nc0 + 2 * j][dr]);
      const unsigned hi = f2b(tsm[nc0 + 2 * j + 1][dr]);
      pk[j] = lo | (hi << 16);
    }
    uint4* dst = (uint4*)(wbT + (size_t)(db * 64 + dr) * 8192 + nb * 64 + nc0);
    uint4 w0, w1;
    w0.x = pk[0]; w0.y = pk[1]; w0.z = pk[2]; w0.w = pk[3];
    w1.x = pk[4]; w1.y = pk[5]; w1.z = pk[6]; w1.w = pk[7];
    dst[0] = w0;
    dst[1] = w1;
  } else if (b < 10240) {  // emb norm
    const int n = b - 2048;
    const float4 v = ((const float4*)(emb + (size_t)n * 1024))[t];
    float ss = v.x * v.x + v.y * v.y + v.z * v.z + v.w * v.w;
#pragma unroll
    for (int off = 1; off < 64; off <<= 1) ss += __shfl_xor(ss, off, 64);
    __shared__ float wsum[4];
    if ((t & 63) == 0) wsum[t >> 6] = ss;
    __syncthreads();
    const float denom = sqrtf(wsum[0] + wsum[1] + wsum[2] + wsum[3]) + 1e-8f;
    ushort4 o;
    o.x = f2b(v.x / denom);
    o.y = f2b(v.y / denom);
    o.z = f2b(v.z / denom);
    o.w = f2b(v.w / denom);
    ((ushort4*)(eb + (size_t)n * 1024))[t] = o;
  } else {  // casts
    const float* src;
    unsigned short* dst;
    int i;
    if (b < 18432) { src = w_read; dst = rb; i = (b - 10240) * 256 + t; }
    else if (b < 20480) { src = h; dst = hb; i = (b - 18432) * 256 + t; }
    else { src = x; dst = xb; i = (b - 20480) * 256 + t; }
    const float4 v = ((const float4*)src)[i];
    ushort4 o;
    o.x = f2b(v.x);
    o.y = f2b(v.y);
    o.z = f2b(v.z);
    o.w = f2b(v.w);
    ((ushort4*)dst)[i] = o;
  }
}

// ==================== stats (64x128 tiles, full-GPU grid) ====================

template <int TROWS>
static __device__ __forceinline__ void stage_tile(const unsigned short* __restrict__ src,
                                                  int row0, int k0, int ld,
                                                  unsigned short* lds, int wave, int lane) {
  const int rsub = lane >> 3;
  const int csub = (lane & 7) << 3;
#pragma unroll
  for (int q = 0; q < TROWS / 32; ++q) {
    const int p = q * 4 + wave;
    const unsigned short* g =
        src + (size_t)(row0 + p * 8 + rsub) * (size_t)ld + (size_t)(k0 + csub);
    GLOAD_LDS(g, lds + p * 512);
  }
}

__global__ __launch_bounds__(256, 2) void k_stats(const unsigned short* __restrict__ hb,
                                                  const unsigned short* __restrict__ eb,
                                                  float* __restrict__ stat_s,
                                                  float* __restrict__ stat_q) {
  __shared__ unsigned short a_sm[64 * 64];
  __shared__ unsigned short b_sm[128 * 64];
  __shared__ float red_s[2][64];
  __shared__ float red_q[2][64];
  const int t = threadIdx.x;
  const int wave = t >> 6, lane = t & 63;
  const int wr = wave >> 1, wc = wave & 1;
  const int m0 = blockIdx.x * 64, n0 = blockIdx.y * 128;
  const int arow = lane & 15;
  const int kcol = (lane >> 4) << 3;
  f32x4 acc[2][4];
#pragma unroll
  for (int m = 0; m < 2; ++m)
#pragma unroll
    for (int n = 0; n < 4; ++n) acc[m][n] = (f32x4)0.0f;
  for (int k0 = 0; k0 < 1024; k0 += 64) {
    stage_tile<64>(hb, m0, k0, 1024, a_sm, wave, lane);
    stage_tile<128>(eb, n0, k0, 1024, b_sm, wave, lane);
    asm volatile("s_waitcnt vmcnt(0)" ::: "memory");
    __syncthreads();
#pragma unroll
    for (int ks = 0; ks < 2; ++ks) {
      bf16x8 af[2], bfr[4];
#pragma unroll
      for (int m = 0; m < 2; ++m)
        af[m] = *(const bf16x8*)&a_sm[(wr * 32 + m * 16 + arow) * 64 + ks * 32 + kcol];
#pragma unroll
      for (int n = 0; n < 4; ++n)
        bfr[n] = *(const bf16x8*)&b_sm[(wc * 64 + n * 16 + arow) * 64 + ks * 32 + kcol];
#pragma unroll
      for (int m = 0; m < 2; ++m)
#pragma unroll
        for (int n = 0; n < 4; ++n)
          acc[m][n] = MFMA_BF16(af[m], bfr[n], acc[m][n], 0, 0, 0);
    }
    __syncthreads();
  }

  float s_r[2][4], q_r[2][4];
#pragma unroll
  for (int m = 0; m < 2; ++m)
#pragma unroll
    for (int i = 0; i < 4; ++i) { s_r[m][i] = 0.f; q_r[m][i] = 0.f; }
#pragma unroll
  for (int m = 0; m < 2; ++m)
#pragma unroll
    for (int n = 0; n < 4; ++n)
#pragma unroll
      for (int i = 0; i < 4; ++i) {
        const float scf = b2f(f2b(acc[m][n][i]));
        s_r[m][i] += scf;
        q_r[m][i] += b2f(f2b(scf * scf));
      }
#pragma unroll
  for (int m = 0; m < 2; ++m)
#pragma unroll
    for (int i = 0; i < 4; ++i) {
      float s = s_r[m][i], q = q_r[m][i];
      for (int off = 1; off < 16; off <<= 1) {
        s += __shfl_xor(s, off, 64);
        q += __shfl_xor(q, off, 64);
      }
      if ((lane & 15) == 0) {
        const int rloc = wr * 32 + m * 16 + (lane >> 4) * 4 + i;
        red_s[wc][rloc] = s;
        red_q[wc][rloc] = q;
      }
    }
  __syncthreads();
  if (t < 64) {
    stat_s[(size_t)(m0 + t) * 8 + blockIdx.y] = red_s[0][t] + red_s[1][t];
    stat_q[(size_t)(m0 + t) * 8 + blockIdx.y] = red_q[0][t] + red_q[1][t];
  }
}

__global__ void k_tau(const float* __restrict__ stat_s, const float* __restrict__ stat_q,
                      const float* __restrict__ tau_off, float* __restrict__ tau) {
  const int r = blockIdx.x * 256 + threadIdx.x;
  if (r >= MDIM) return;
  float S = 0.f, Q = 0.f;
#pragma unroll
  for (int j = 0; j < 8; ++j) {
    S += stat_s[(size_t)r * 8 + j];
    Q += stat_q[(size_t)r * 8 + j];
  }
  const float s_sum = S * 8.0f;
  const float sq_sum = Q * 8.0f;
  const float mean = s_sum * (1.0f / 8192.0f);
  const float var = __fsub_rn(sq_sum * (1.0f / 8192.0f), __fmul_rn(mean, mean));
  const float sd = __fadd_rn(__fsqrt_rn(var), 1e-8f);
  const float tv = __fadd_rn(mean, __fmul_rn(tau_off[r], sd));
  tau[r] = b2f(f2b(tv));
}

// ==================== k_sc: sc GEMM + gating -> eg (repacked), es/em ====================

__global__ __launch_bounds__(512, 2) void k_sc(const unsigned short* __restrict__ hb,
                                               const unsigned short* __restrict__ eb,
                                               const float* __restrict__ tau,
                                               unsigned short* __restrict__ Aeg,
                                               float* __restrict__ es_part,
                                               float* __restrict__ em_part) {
  __shared__ __align__(16) char lds[131072];
  __shared__ float tau_sm[256];
  __shared__ float red_es[1024];
  __shared__ float red_em[1024];
  const int t = threadIdx.x, w = t >> 6, l = t & 63;
  const int wr = w >> 2, wc = w & 3;
  const int bid = blockIdx.x;
  const int swz = (bid & 7) * 32 + (bid >> 3);
  const int m0 = (swz >> 5) * 256, n0 = (swz & 31) * 256;
  f32x4 acc[8][4];
#pragma unroll
  for (int m = 0; m < 8; ++m)
#pragma unroll
    for (int n = 0; n < 4; ++n) acc[m][n] = (f32x4)0.0f;
  gemm256(hb, eb, 1024, m0, n0, 0, lds, acc, w, l, wr, wc);

  __syncthreads();
  if (t < 256) tau_sm[t] = tau[m0 + t];
  __syncthreads();
  const int lrow = l & 15, lk = l >> 4;
#pragma unroll
  for (int m = 0; m < 8; ++m) {
#pragma unroll
    for (int i = 0; i < 4; ++i) {
      const int rl = wr * 128 + m * 16 + lk * 4 + i;
      const float taub = tau_sm[rl];
      const int sw = SWR(rl);
      float es_v = 0.f, em_v = 0.f;
#pragma unroll
      for (int n = 0; n < 4; ++n) {
        const float scf = b2f(f2b(acc[m][n][i]));
        const float rawf = b2f(f2b(scf - taub));
        float gcf;
        if (rawf > 0.f) gcf = fminf(rawf, 10.0f);
        else gcf = b2f(f2b(1e-6f * expf(fmaxf(rawf, -10.0f))));
        const unsigned short egu = f2b(expf(gcf) - 1.0f);
        const float ef = b2f(egu);
        es_v += ef;
        em_v = fmaxf(em_v, ef);
        const int cl = wc * 64 + n * 16 + lrow;
        *(unsigned short*)(lds + rl * 512 + ((2 * cl) ^ sw)) = egu;
      }
      for (int off = 1; off < 16; off <<= 1) {
        es_v += __shfl_xor(es_v, off, 64);
        em_v = fmaxf(em_v, __shfl_xor(em_v, off, 64));
      }
      if (lrow == 0) {
        red_es[wc * 256 + rl] = es_v;
        red_em[wc * 256 + rl] = em_v;
      }
    }
  }
  __syncthreads();
  if (t < 256) {
    const float s = red_es[t] + red_es[256 + t] + red_es[512 + t] + red_es[768 + t];
    const float e = fmaxf(fmaxf(red_em[t], red_em[256 + t]),
                          fmaxf(red_em[512 + t], red_em[768 + t]));
    es_part[(size_t)(m0 + t) * 32 + (n0 >> 8)] = s;
    em_part[(size_t)(m0 + t) * 32 + (n0 >> 8)] = e;
  }
  const int r = t >> 1, hh = t & 1;
  const int swr = SWR(r);
#pragma unroll 4
  for (int j = 0; j < 16; ++j) {
    const uint4 v = *(const uint4*)(lds + r * 512 + ((hh * 256 + 16 * j) ^ swr));
    *(uint4*)(Aeg + (size_t)(m0 + r) * NDIM + n0 + hh * 128 + 8 * j) = v;
  }
}

// ==================== k_xr: xr GEMM, A = bf16(eg * xr) (coalesced RMW) ====================

__global__ __launch_bounds__(512, 2) void k_xr(const unsigned short* __restrict__ xb,
                                               const unsigned short* __restrict__ rb,
                                               unsigned short* __restrict__ Aeg) {
  __shared__ __align__(16) char lds[131072];
  const int t = threadIdx.x, w = t >> 6, l = t & 63;
  const int wr = w >> 2, wc = w & 3;
  const int bid = blockIdx.x;
  const int swz = (bid & 7) * 32 + (bid >> 3);
  const int m0 = (swz >> 5) * 256, n0 = (swz & 31) * 256;
  f32x4 acc[8][4];
#pragma unroll
  for (int m = 0; m < 8; ++m)
#pragma unroll
    for (int n = 0; n < 4; ++n) acc[m][n] = (f32x4)0.0f;
  gemm256(xb, rb, 1024, m0, n0, 0, lds, acc, w, l, wr, wc);

  __syncthreads();
  const int lrow = l & 15, lk = l >> 4;
#pragma unroll
  for (int m = 0; m < 8; ++m)
#pragma unroll
    for (int i = 0; i < 4; ++i) {
      const int rl = wr * 128 + m * 16 + lk * 4 + i;
      const int sw = SWR(rl);
#pragma unroll
      for (int n = 0; n < 4; ++n) {
        const int cl = wc * 64 + n * 16 + lrow;
        *(unsigned short*)(lds + rl * 512 + ((2 * cl) ^ sw)) = f2b(acc[m][n][i]);
      }
    }
  __syncthreads();
  const int r = t >> 1, hh = t & 1;
  const int swr = SWR(r);
#pragma unroll 4
  for (int j = 0; j < 16; ++j) {
    unsigned short* p = Aeg + (size_t)(m0 + r) * NDIM + n0 + hh * 128 + 8 * j;
    const uint4 eg = *(const uint4*)p;
    const uint4 xr = *(const uint4*)(lds + r * 512 + ((hh * 256 + 16 * j) ^ swr));
    uint4 o;
    o.x = bmul2(eg.x, xr.x);
    o.y = bmul2(eg.y, xr.y);
    o.z = bmul2(eg.z, xr.z);
    o.w = bmul2(eg.w, xr.w);
    *(uint4*)p = o;
  }
}

// ==================== k_out: per-chunk GEMM -> bf16 partial (repacked) ====================

__global__ __launch_bounds__(512, 2) void k_out(const unsigned short* __restrict__ A,
                                                const unsigned short* __restrict__ wbT,
                                                unsigned short* __restrict__ pacc) {
  __shared__ __align__(16) char lds[131072];
  const int t = threadIdx.x, w = t >> 6, l = t & 63;
  const int wr = w >> 2, wc = w & 3;
  // chunk-per-XCD: per-XCD working set = A-chunk 4MB + wbT-chunk 2MB.
  const int bid = blockIdx.x;
  const int chunk = bid & 7, rrest = bid >> 3;
  const int bm = rrest >> 2, bd = rrest & 3;
  const int m0 = bm * 256, d0 = bd * 256;
  f32x4 acc[8][4];
#pragma unroll
  for (int m = 0; m < 8; ++m)
#pragma unroll
    for (int n = 0; n < 4; ++n) acc[m][n] = (f32x4)0.0f;
  gemm256(A, wbT, 8192, m0, d0, chunk * 1024, lds, acc, w, l, wr, wc);

  __syncthreads();
  const int lrow = l & 15, lk = l >> 4;
#pragma unroll
  for (int m = 0; m < 8; ++m)
#pragma unroll
    for (int i = 0; i < 4; ++i) {
      const int rl = wr * 128 + m * 16 + lk * 4 + i;
      const int sw = SWR(rl);
#pragma unroll
      for (int n = 0; n < 4; ++n) {
        const int cl = wc * 64 + n * 16 + lrow;
        *(unsigned short*)(lds + rl * 512 + ((2 * cl) ^ sw)) = f2b(acc[m][n][i]);
      }
    }
  __syncthreads();
  const int r = t >> 1, hh = t & 1;
  const int swr = SWR(r);
#pragma unroll 4
  for (int j = 0; j < 16; ++j) {
    const uint4 v = *(const uint4*)(lds + r * 512 + ((hh * 256 + 16 * j) ^ swr));
    *(uint4*)(pacc + ((size_t)chunk * MDIM + m0 + r) * DDIM + d0 + hh * 128 + 8 * j) = v;
  }
}

// ==================== scales + finish ====================

__global__ void k_scale(const float* __restrict__ es_part, const float* __restrict__ em_part,
                        float* __restrict__ scale2) {
  const int r = blockIdx.x * 256 + threadIdx.x;
  if (r >= MDIM) return;
  float s = 0.f, m = 0.f;
#pragma unroll
  for (int j = 0; j < 32; ++j) {
    s += es_part[(size_t)r * 32 + j];
    m = fmaxf(m, em_part[(size_t)r * 32 + j]);
  }
  scale2[2 * r] = b2f(f2b(1.0f / (s + 1e-8f)));  // inv_es (bf16 value)
  scale2[2 * r + 1] = b2f(f2b(tanhf(m)));        // gs (bf16 value)
}

__global__ __launch_bounds__(256) void k_finish(const unsigned short* __restrict__ pacc,
                                                const float* __restrict__ scale2,
                                                float* __restrict__ outp) {
  const int t = blockIdx.x * 256 + threadIdx.x;
  const int r = t >> 8;
  const int d4 = (t & 255) * 4;
  float sx = 0.f, sy = 0.f, sz = 0.f, sw = 0.f;
#pragma unroll
  for (int c = 0; c < 8; ++c) {
    const ushort4 v = *(const ushort4*)(pacc + ((size_t)c * MDIM + r) * DDIM + d4);
    sx += b2f(v.x);
    sy += b2f(v.y);
    sz += b2f(v.z);
    sw += b2f(v.w);
  }
  const float inv = scale2[2 * r];
  const float gsv = scale2[2 * r + 1];
  float4 o;
  o.x = (sx * inv) * gsv;
  o.y = (sy * inv) * gsv;
  o.z = (sz * inv) * gsv;
  o.w = (sw * inv) * gsv;
  *(float4*)(outp + (size_t)r * DDIM + d4) = o;
}

// ==================== launch ====================

extern "C" void kernel_launch(void* const* d_in, const int* in_sizes, int n_in,
                              void* d_out, int out_size, void* d_ws, size_t ws_size,
                              hipStream_t stream) {
  const float* x = (const float*)d_in[0];
  const float* h = (const float*)d_in[1];
  const float* emb = (const float*)d_in[2];
  const float* tau_off = (const float*)d_in[3];
  const float* w_read = (const float*)d_in[4];
  const float* w_write = (const float*)d_in[5];

  char* ws = (char*)d_ws;
  const size_t MB = 1024 * 1024;
  unsigned short* rb = (unsigned short*)(ws);             // 16 MB [prep -> xr]
  unsigned short* eb = (unsigned short*)(ws + 16 * MB);   // 16 MB [prep -> sc]
  unsigned short* wbT = (unsigned short*)(ws + 32 * MB);  // 16 MB [prep -> out]
  unsigned short* hb = (unsigned short*)(ws + 48 * MB);   // 4 MB
  unsigned short* xb = (unsigned short*)(ws + 52 * MB);   // 4 MB
  unsigned short* Aeg = (unsigned short*)(ws + 56 * MB);  // 32 MB [sc -> xr -> out]
  unsigned short* pacc = (unsigned short*)(ws);           // 32 MB overlay (rb+eb dead)
  float* tau = (float*)(ws + 88 * MB);
  float* stat_s = (float*)(ws + 88 * MB + 1 * 65536);
  float* stat_q = (float*)(ws + 88 * MB + 2 * 65536);
  float* es_part = (float*)(ws + 88 * MB + 3 * 65536);    // 256 KB
  float* em_part = (float*)(ws + 88 * MB + 7 * 65536);    // 256 KB
  float* scale2 = (float*)(ws + 88 * MB + 11 * 65536);    // 16 KB
  if (ws_size < 88 * MB + 12 * 65536) return;
  float* outp = (float*)d_out;

  k_prep<<<22528, 256, 0, stream>>>(emb, w_read, h, x, w_write, eb, rb, hb, xb, wbT);
  k_stats<<<dim3(MDIM / 64, 8), 256, 0, stream>>>(hb, eb, stat_s, stat_q);
  k_tau<<<MDIM / 256, 256, 0, stream>>>(stat_s, stat_q, tau_off, tau);
  k_sc<<<256, 512, 0, stream>>>(hb, eb, tau, Aeg, es_part, em_part);
  k_scale<<<MDIM / 256, 256, 0, stream>>>(es_part, em_part, scale2);
  k_xr<<<256, 512, 0, stream>>>(xb, rb, Aeg);
  k_out<<<256, 512, 0, stream>>>(Aeg, wbT, pacc);
  k_finish<<<(MDIM * DDIM / 4) / 256, 256, 0, stream>>>(pacc, scale2, outp);
}

// Round 10
// 236.727 us; speedup vs baseline: 1.0395x; 1.0395x over previous
//
#include <hip/hip_runtime.h>

// DAWN_14886356647950: fused gated sparse read-write (B=2,S=1024,D=1024,N=8192,NC=8)
// R9: R7 base (best, 190.6us; R8 epilogue-repack reverted) + k_sc/k_xr fused into
// k_gate with eg held in 64 packed VGPRs (no global eg round-trip). Everything
// else byte-identical to R7 (2-phase gemm256, scattered A-write, R7 k_out).

#define MDIM 2048
#define DDIM 1024
#define NDIM 8192

typedef __attribute__((ext_vector_type(8))) __bf16 bf16x8;
typedef __attribute__((ext_vector_type(4))) float f32x4;

static __device__ __forceinline__ unsigned short f2b(float f) {
  unsigned u = __float_as_uint(f);
  u = (u + 0x7FFFu + ((u >> 16) & 1u)) >> 16;  // RTNE
  return (unsigned short)u;
}
static __device__ __forceinline__ float b2f(unsigned short s) {
  return __uint_as_float(((unsigned)s) << 16);
}

#define LDSF(off) (*(const bf16x8*)(lds + (off)))
#define MFMA_BF16 __builtin_amdgcn_mfma_f32_16x16x32_bf16

#define GLOAD_LDS(gp, lp)                                                              \
  __builtin_amdgcn_global_load_lds(                                                    \
      (const __attribute__((address_space(1))) unsigned int*)(const void*)(gp),        \
      (__attribute__((address_space(3))) unsigned int*)(void*)(lp), 16, 0, 0)

// Stage one 128x64 half-tile (16KB); LDS dest linear (wave-uniform base + lane*16B),
// swizzle via permuted per-lane GLOBAL source column (involution with read-side XOR).
static __device__ __forceinline__ void stage_half(const unsigned short* __restrict__ src,
                                                  int ld, int row0, int k0,
                                                  char* lds, int lds_off, int w, int l) {
  const int rsub = l >> 3;
  const int col = k0 + 8 * ((l & 7) ^ rsub);
#pragma unroll
  for (int j = 0; j < 2; ++j) {
    const unsigned short* g =
        src + (size_t)(row0 + w * 8 + j * 64 + rsub) * (size_t)ld + col;
    GLOAD_LDS(g, lds + lds_off + j * 8192 + w * 1024);
  }
}

static __device__ __forceinline__ void stage4(const unsigned short* __restrict__ asrc,
                                              const unsigned short* __restrict__ bsrc,
                                              int ld, int m0, int n0, int k0,
                                              char* lds, int buf, int w, int l) {
  stage_half(asrc, ld, m0,       k0, lds, buf,         w, l);
  stage_half(asrc, ld, m0 + 128, k0, lds, buf + 16384, w, l);
  stage_half(bsrc, ld, n0,       k0, lds, buf + 32768, w, l);
  stage_half(bsrc, ld, n0 + 128, k0, lds, buf + 49152, w, l);
}

// 256x256 x K=1024 (16 tiles) NT-GEMM, 8 waves (2M x 4N), per-wave 128x64.
// 2-phase: per tile {stage t+1 -> buf^1 ; read frags of t ; lgkm0 ; 64 MFMA ;
// vmcnt(0) ; barrier}.
static __device__ __forceinline__ void gemm256(const unsigned short* __restrict__ asrc,
                                               const unsigned short* __restrict__ bsrc,
                                               int ld, int m0, int n0, int kbase,
                                               char* lds, f32x4 (&acc)[8][4],
                                               int w, int l, int wr, int wc) {
  const int lrow = l & 15, lk = l >> 4;
  const int axor = (l & 7) << 4;
  const int kx0 = (lk << 4) ^ axor;        // ks=0 swizzled k-byte
  const int kx1 = (64 | (lk << 4)) ^ axor; // ks=1
  const int arow_off = lrow * 128;
  const int brow_off = ((wc & 1) * 64 + lrow) * 128;

  stage4(asrc, bsrc, ld, m0, n0, kbase, lds, 0, w, l);
  asm volatile("s_waitcnt vmcnt(0)" ::: "memory");
  __builtin_amdgcn_s_barrier();

#pragma unroll 1
  for (int t = 0; t < 16; ++t) {
    const int buf = (t & 1) * 65536;
    const int nbuf = 65536 - buf;
    if (t < 15) stage4(asrc, bsrc, ld, m0, n0, kbase + (t + 1) * 64, lds, nbuf, w, l);

    const int ab = buf + wr * 16384;
    const int bb = buf + 32768 + (wc >> 1) * 16384;
    bf16x8 aLO[4][2], aHI[4][2], bLO[2][2], bHI[2][2];
#pragma unroll
    for (int m = 0; m < 4; ++m) {
      aLO[m][0] = LDSF(ab + arow_off + m * 2048 + kx0);
      aLO[m][1] = LDSF(ab + arow_off + m * 2048 + kx1);
    }
#pragma unroll
    for (int n = 0; n < 2; ++n) {
      bLO[n][0] = LDSF(bb + brow_off + n * 2048 + kx0);
      bLO[n][1] = LDSF(bb + brow_off + n * 2048 + kx1);
      bHI[n][0] = LDSF(bb + brow_off + (n + 2) * 2048 + kx0);
      bHI[n][1] = LDSF(bb + brow_off + (n + 2) * 2048 + kx1);
    }
    asm volatile("s_waitcnt lgkmcnt(0)" ::: "memory");
    __builtin_amdgcn_s_setprio(1);
#pragma unroll
    for (int ks = 0; ks < 2; ++ks)
#pragma unroll
      for (int n = 0; n < 2; ++n)
#pragma unroll
        for (int m = 0; m < 4; ++m)
          acc[m][n] = MFMA_BF16(aLO[m][ks], bLO[n][ks], acc[m][n], 0, 0, 0);
    __builtin_amdgcn_s_setprio(0);
#pragma unroll
    for (int m = 0; m < 4; ++m) {
      aHI[m][0] = LDSF(ab + arow_off + (m + 4) * 2048 + kx0);
      aHI[m][1] = LDSF(ab + arow_off + (m + 4) * 2048 + kx1);
    }
    __builtin_amdgcn_s_setprio(1);
#pragma unroll
    for (int ks = 0; ks < 2; ++ks)
#pragma unroll
      for (int n = 0; n < 2; ++n)
#pragma unroll
        for (int m = 0; m < 4; ++m)
          acc[m][n + 2] = MFMA_BF16(aLO[m][ks], bHI[n][ks], acc[m][n + 2], 0, 0, 0);
    __builtin_amdgcn_s_setprio(0);
    asm volatile("s_waitcnt lgkmcnt(0)" ::: "memory");
    __builtin_amdgcn_s_setprio(1);
#pragma unroll
    for (int ks = 0; ks < 2; ++ks)
#pragma unroll
      for (int n = 0; n < 2; ++n)
#pragma unroll
        for (int m = 0; m < 4; ++m)
          acc[m + 4][n + 2] = MFMA_BF16(aHI[m][ks], bHI[n][ks], acc[m + 4][n + 2], 0, 0, 0);
#pragma unroll
    for (int ks = 0; ks < 2; ++ks)
#pragma unroll
      for (int n = 0; n < 2; ++n)
#pragma unroll
        for (int m = 0; m < 4; ++m)
          acc[m + 4][n] = MFMA_BF16(aHI[m][ks], bLO[n][ks], acc[m + 4][n], 0, 0, 0);
    __builtin_amdgcn_s_setprio(0);
    asm volatile("s_waitcnt vmcnt(0)" ::: "memory");  // t+1 fully staged
    __builtin_amdgcn_s_barrier();
  }
}

// ==================== fused prep (single dispatch) ====================
// [0,2048): w_write transpose; [2048,10240): emb norm; [10240,22528): casts.

__global__ __launch_bounds__(256) void k_prep(const float* __restrict__ emb,
                                              const float* __restrict__ w_read,
                                              const float* __restrict__ h,
                                              const float* __restrict__ x,
                                              const float* __restrict__ w_write,
                                              unsigned short* __restrict__ eb,
                                              unsigned short* __restrict__ rb,
                                              unsigned short* __restrict__ hb,
                                              unsigned short* __restrict__ xb,
                                              unsigned short* __restrict__ wbT) {
  const int b = blockIdx.x, t = threadIdx.x;
  if (b < 2048) {  // w_write transpose
    __shared__ float tsm[64][65];
    const int nb = b & 127, db = b >> 7;
    const int r = t >> 2, c4 = (t & 3) * 16;
#pragma unroll
    for (int j = 0; j < 4; ++j) {
      const float4 v = *(const float4*)&w_write[(size_t)(nb * 64 + r) * 1024 + db * 64 + c4 + 4 * j];
      tsm[r][c4 + 4 * j + 0] = v.x;
      tsm[r][c4 + 4 * j + 1] = v.y;
      tsm[r][c4 + 4 * j + 2] = v.z;
      tsm[r][c4 + 4 * j + 3] = v.w;
    }
    __syncthreads();
    const int dr = t >> 2, nc0 = (t & 3) * 16;
    unsigned pk[8];
#pragma unroll
    for (int j = 0; j < 8; ++j) {
      const unsigned lo = f2b(tsm[nc0 + 2 * j][dr]);
      const unsigned hi = f2b(tsm[nc0 + 2 * j + 1][dr]);
      pk[j] = lo | (hi << 16);
    }
    uint4* dst = (uint4*)(wbT + (size_t)(db * 64 + dr) * 8192 + nb * 64 + nc0);
    uint4 w0, w1;
    w0.x = pk[0]; w0.y = pk[1]; w0.z = pk[2]; w0.w = pk[3];
    w1.x = pk[4]; w1.y = pk[5]; w1.z = pk[6]; w1.w = pk[7];
    dst[0] = w0;
    dst[1] = w1;
  } else if (b < 10240) {  // emb norm
    const int n = b - 2048;
    const float4 v = ((const float4*)(emb + (size_t)n * 1024))[t];
    float ss = v.x * v.x + v.y * v.y + v.z * v.z + v.w * v.w;
#pragma unroll
    for (int off = 1; off < 64; off <<= 1) ss += __shfl_xor(ss, off, 64);
    __shared__ float wsum[4];
    if ((t & 63) == 0) wsum[t >> 6] = ss;
    __syncthreads();
    const float denom = sqrtf(wsum[0] + wsum[1] + wsum[2] + wsum[3]) + 1e-8f;
    ushort4 o;
    o.x = f2b(v.x / denom);
    o.y = f2b(v.y / denom);
    o.z = f2b(v.z / denom);
    o.w = f2b(v.w / denom);
    ((ushort4*)(eb + (size_t)n * 1024))[t] = o;
  } else {  // casts
    const float* src;
    unsigned short* dst;
    int i;
    if (b < 18432) { src = w_read; dst = rb; i = (b - 10240) * 256 + t; }
    else if (b < 20480) { src = h; dst = hb; i = (b - 18432) * 256 + t; }
    else { src = x; dst = xb; i = (b - 20480) * 256 + t; }
    const float4 v = ((const float4*)src)[i];
    ushort4 o;
    o.x = f2b(v.x);
    o.y = f2b(v.y);
    o.z = f2b(v.z);
    o.w = f2b(v.w);
    ((ushort4*)dst)[i] = o;
  }
}

// ==================== stats (64x128 tiles, full-GPU grid) ====================

template <int TROWS>
static __device__ __forceinline__ void stage_tile(const unsigned short* __restrict__ src,
                                                  int row0, int k0, int ld,
                                                  unsigned short* lds, int wave, int lane) {
  const int rsub = lane >> 3;
  const int csub = (lane & 7) << 3;
#pragma unroll
  for (int q = 0; q < TROWS / 32; ++q) {
    const int p = q * 4 + wave;
    const unsigned short* g =
        src + (size_t)(row0 + p * 8 + rsub) * (size_t)ld + (size_t)(k0 + csub);
    GLOAD_LDS(g, lds + p * 512);
  }
}

__global__ __launch_bounds__(256, 2) void k_stats(const unsigned short* __restrict__ hb,
                                                  const unsigned short* __restrict__ eb,
                                                  float* __restrict__ stat_s,
                                                  float* __restrict__ stat_q) {
  __shared__ unsigned short a_sm[64 * 64];
  __shared__ unsigned short b_sm[128 * 64];
  __shared__ float red_s[2][64];
  __shared__ float red_q[2][64];
  const int t = threadIdx.x;
  const int wave = t >> 6, lane = t & 63;
  const int wr = wave >> 1, wc = wave & 1;
  const int m0 = blockIdx.x * 64, n0 = blockIdx.y * 128;
  const int arow = lane & 15;
  const int kcol = (lane >> 4) << 3;
  f32x4 acc[2][4];
#pragma unroll
  for (int m = 0; m < 2; ++m)
#pragma unroll
    for (int n = 0; n < 4; ++n) acc[m][n] = (f32x4)0.0f;
  for (int k0 = 0; k0 < 1024; k0 += 64) {
    stage_tile<64>(hb, m0, k0, 1024, a_sm, wave, lane);
    stage_tile<128>(eb, n0, k0, 1024, b_sm, wave, lane);
    asm volatile("s_waitcnt vmcnt(0)" ::: "memory");
    __syncthreads();
#pragma unroll
    for (int ks = 0; ks < 2; ++ks) {
      bf16x8 af[2], bfr[4];
#pragma unroll
      for (int m = 0; m < 2; ++m)
        af[m] = *(const bf16x8*)&a_sm[(wr * 32 + m * 16 + arow) * 64 + ks * 32 + kcol];
#pragma unroll
      for (int n = 0; n < 4; ++n)
        bfr[n] = *(const bf16x8*)&b_sm[(wc * 64 + n * 16 + arow) * 64 + ks * 32 + kcol];
#pragma unroll
      for (int m = 0; m < 2; ++m)
#pragma unroll
        for (int n = 0; n < 4; ++n)
          acc[m][n] = MFMA_BF16(af[m], bfr[n], acc[m][n], 0, 0, 0);
    }
    __syncthreads();
  }

  float s_r[2][4], q_r[2][4];
#pragma unroll
  for (int m = 0; m < 2; ++m)
#pragma unroll
    for (int i = 0; i < 4; ++i) { s_r[m][i] = 0.f; q_r[m][i] = 0.f; }
#pragma unroll
  for (int m = 0; m < 2; ++m)
#pragma unroll
    for (int n = 0; n < 4; ++n)
#pragma unroll
      for (int i = 0; i < 4; ++i) {
        const float scf = b2f(f2b(acc[m][n][i]));
        s_r[m][i] += scf;
        q_r[m][i] += b2f(f2b(scf * scf));
      }
#pragma unroll
  for (int m = 0; m < 2; ++m)
#pragma unroll
    for (int i = 0; i < 4; ++i) {
      float s = s_r[m][i], q = q_r[m][i];
      for (int off = 1; off < 16; off <<= 1) {
        s += __shfl_xor(s, off, 64);
        q += __shfl_xor(q, off, 64);
      }
      if ((lane & 15) == 0) {
        const int rloc = wr * 32 + m * 16 + (lane >> 4) * 4 + i;
        red_s[wc][rloc] = s;
        red_q[wc][rloc] = q;
      }
    }
  __syncthreads();
  if (t < 64) {
    stat_s[(size_t)(m0 + t) * 8 + blockIdx.y] = red_s[0][t] + red_s[1][t];
    stat_q[(size_t)(m0 + t) * 8 + blockIdx.y] = red_q[0][t] + red_q[1][t];
  }
}

__global__ void k_tau(const float* __restrict__ stat_s, const float* __restrict__ stat_q,
                      const float* __restrict__ tau_off, float* __restrict__ tau) {
  const int r = blockIdx.x * 256 + threadIdx.x;
  if (r >= MDIM) return;
  float S = 0.f, Q = 0.f;
#pragma unroll
  for (int j = 0; j < 8; ++j) {
    S += stat_s[(size_t)r * 8 + j];
    Q += stat_q[(size_t)r * 8 + j];
  }
  const float s_sum = S * 8.0f;
  const float sq_sum = Q * 8.0f;
  const float mean = s_sum * (1.0f / 8192.0f);
  const float var = __fsub_rn(sq_sum * (1.0f / 8192.0f), __fmul_rn(mean, mean));
  const float sd = __fadd_rn(__fsqrt_rn(var), 1e-8f);
  const float tv = __fadd_rn(mean, __fmul_rn(tau_off[r], sd));
  tau[r] = b2f(f2b(tv));
}

// ==================== k_gate: sc GEMM + gating (eg in regs) + xr GEMM + A ====================

__global__ __launch_bounds__(512, 2) void k_gate(const unsigned short* __restrict__ hb,
                                                 const unsigned short* __restrict__ eb,
                                                 const unsigned short* __restrict__ xb,
                                                 const unsigned short* __restrict__ rb,
                                                 const float* __restrict__ tau,
                                                 unsigned short* __restrict__ Aeg,
                                                 float* __restrict__ es_part,
                                                 float* __restrict__ em_part) {
  __shared__ __align__(16) char lds[131072];
  __shared__ float tau_sm[256];
  __shared__ float red_es[1024];
  __shared__ float red_em[1024];
  const int t = threadIdx.x, w = t >> 6, l = t & 63;
  const int wr = w >> 2, wc = w & 3;
  const int bid = blockIdx.x;
  const int swz = (bid & 7) * 32 + (bid >> 3);
  const int m0 = (swz >> 5) * 256, n0 = (swz & 31) * 256;
  const int lrow = l & 15, lk = l >> 4;

  f32x4 acc[8][4];
#pragma unroll
  for (int m = 0; m < 8; ++m)
#pragma unroll
    for (int n = 0; n < 4; ++n) acc[m][n] = (f32x4)0.0f;
  gemm256(hb, eb, 1024, m0, n0, 0, lds, acc, w, l, wr, wc);

  // --- gating: eg -> 64 packed VGPRs; es/em partials ---
  __syncthreads();
  if (t < 256) tau_sm[t] = tau[m0 + t];
  __syncthreads();
  unsigned eg_pk[8][4][2];
#pragma unroll
  for (int m = 0; m < 8; ++m) {
#pragma unroll
    for (int i = 0; i < 4; ++i) {
      const int rl = wr * 128 + m * 16 + lk * 4 + i;
      const float taub = tau_sm[rl];
      float es_v = 0.f, em_v = 0.f;
      unsigned p0 = 0, p1 = 0;
#pragma unroll
      for (int n = 0; n < 4; ++n) {
        const float scf = b2f(f2b(acc[m][n][i]));
        const float rawf = b2f(f2b(scf - taub));
        float gcf;
        if (rawf > 0.f) gcf = fminf(rawf, 10.0f);
        else gcf = b2f(f2b(1e-6f * expf(fmaxf(rawf, -10.0f))));
        const unsigned short egu = f2b(expf(gcf) - 1.0f);
        const float ef = b2f(egu);
        es_v += ef;
        em_v = fmaxf(em_v, ef);
        if (n < 2) p0 |= ((unsigned)egu) << (16 * n);
        else       p1 |= ((unsigned)egu) << (16 * (n - 2));
      }
      eg_pk[m][i][0] = p0;
      eg_pk[m][i][1] = p1;
      for (int off = 1; off < 16; off <<= 1) {
        es_v += __shfl_xor(es_v, off, 64);
        em_v = fmaxf(em_v, __shfl_xor(em_v, off, 64));
      }
      if (lrow == 0) {
        red_es[wc * 256 + rl] = es_v;
        red_em[wc * 256 + rl] = em_v;
      }
    }
  }
  __syncthreads();
  if (t < 256) {
    const float s = red_es[t] + red_es[256 + t] + red_es[512 + t] + red_es[768 + t];
    const float e = fmaxf(fmaxf(red_em[t], red_em[256 + t]),
                          fmaxf(red_em[512 + t], red_em[768 + t]));
    es_part[(size_t)(m0 + t) * 32 + (n0 >> 8)] = s;
    em_part[(size_t)(m0 + t) * 32 + (n0 >> 8)] = e;
  }

  // --- xr GEMM (lds reuse is safe: gemm prologue vmcnt+barrier republishes) ---
#pragma unroll
  for (int m = 0; m < 8; ++m)
#pragma unroll
    for (int n = 0; n < 4; ++n) acc[m][n] = (f32x4)0.0f;
  gemm256(xb, rb, 1024, m0, n0, 0, lds, acc, w, l, wr, wc);

  // --- A = bf16(eg * bf16(xr)), eg from registers ---
#pragma unroll
  for (int m = 0; m < 8; ++m)
#pragma unroll
    for (int n = 0; n < 4; ++n)
#pragma unroll
      for (int i = 0; i < 4; ++i) {
        const int rl = wr * 128 + m * 16 + lk * 4 + i;
        const unsigned short egu =
            (unsigned short)((eg_pk[m][i][n >> 1] >> (16 * (n & 1))) & 0xFFFFu);
        const float xrf = b2f(f2b(acc[m][n][i]));
        Aeg[(size_t)(m0 + rl) * NDIM + (size_t)(n0 + wc * 64 + n * 16 + lrow)] =
            f2b(b2f(egu) * xrf);
      }
}

// ==================== k_out: per-chunk GEMM -> bf16 partial ====================

__global__ __launch_bounds__(512, 2) void k_out(const unsigned short* __restrict__ A,
                                                const unsigned short* __restrict__ wbT,
                                                unsigned short* __restrict__ pacc) {
  __shared__ __align__(16) char lds[131072];
  const int t = threadIdx.x, w = t >> 6, l = t & 63;
  const int wr = w >> 2, wc = w & 3;
  const int bid = blockIdx.x;
  const int swz = (bid & 7) * 32 + (bid >> 3);
  const int bm = swz >> 5, chunk = (swz >> 2) & 7, bd = swz & 3;
  const int m0 = bm * 256, d0 = bd * 256;
  f32x4 acc[8][4];
#pragma unroll
  for (int m = 0; m < 8; ++m)
#pragma unroll
    for (int n = 0; n < 4; ++n) acc[m][n] = (f32x4)0.0f;
  gemm256(A, wbT, 8192, m0, d0, chunk * 1024, lds, acc, w, l, wr, wc);

  const int lrow = l & 15, lk = l >> 4;
#pragma unroll
  for (int m = 0; m < 8; ++m)
#pragma unroll
    for (int n = 0; n < 4; ++n)
#pragma unroll
      for (int i = 0; i < 4; ++i) {
        const int rl = wr * 128 + m * 16 + lk * 4 + i;
        pacc[((size_t)chunk * MDIM + (m0 + rl)) * DDIM +
             (size_t)(d0 + wc * 64 + n * 16 + lrow)] = f2b(acc[m][n][i]);
      }
}

// ==================== scales + finish ====================

__global__ void k_scale(const float* __restrict__ es_part, const float* __restrict__ em_part,
                        float* __restrict__ scale2) {
  const int r = blockIdx.x * 256 + threadIdx.x;
  if (r >= MDIM) return;
  float s = 0.f, m = 0.f;
#pragma unroll
  for (int j = 0; j < 32; ++j) {
    s += es_part[(size_t)r * 32 + j];
    m = fmaxf(m, em_part[(size_t)r * 32 + j]);
  }
  scale2[2 * r] = b2f(f2b(1.0f / (s + 1e-8f)));  // inv_es (bf16 value)
  scale2[2 * r + 1] = b2f(f2b(tanhf(m)));        // gs (bf16 value)
}

__global__ __launch_bounds__(256) void k_finish(const unsigned short* __restrict__ pacc,
                                                const float* __restrict__ scale2,
                                                float* __restrict__ outp) {
  const int t = blockIdx.x * 256 + threadIdx.x;
  const int r = t >> 8;
  const int d4 = (t & 255) * 4;
  float sx = 0.f, sy = 0.f, sz = 0.f, sw = 0.f;
#pragma unroll
  for (int c = 0; c < 8; ++c) {
    const ushort4 v = *(const ushort4*)(pacc + ((size_t)c * MDIM + r) * DDIM + d4);
    sx += b2f(v.x);
    sy += b2f(v.y);
    sz += b2f(v.z);
    sw += b2f(v.w);
  }
  const float inv = scale2[2 * r];
  const float gsv = scale2[2 * r + 1];
  float4 o;
  o.x = (sx * inv) * gsv;
  o.y = (sy * inv) * gsv;
  o.z = (sz * inv) * gsv;
  o.w = (sw * inv) * gsv;
  *(float4*)(outp + (size_t)r * DDIM + d4) = o;
}

// ==================== launch ====================

extern "C" void kernel_launch(void* const* d_in, const int* in_sizes, int n_in,
                              void* d_out, int out_size, void* d_ws, size_t ws_size,
                              hipStream_t stream) {
  const float* x = (const float*)d_in[0];
  const float* h = (const float*)d_in[1];
  const float* emb = (const float*)d_in[2];
  const float* tau_off = (const float*)d_in[3];
  const float* w_read = (const float*)d_in[4];
  const float* w_write = (const float*)d_in[5];

  char* ws = (char*)d_ws;
  const size_t MB = 1024 * 1024;
  unsigned short* rb = (unsigned short*)(ws);             // 16 MB [prep -> gate]
  unsigned short* eb = (unsigned short*)(ws + 16 * MB);   // 16 MB [prep -> gate]
  unsigned short* wbT = (unsigned short*)(ws + 32 * MB);  // 16 MB [prep -> out]
  unsigned short* hb = (unsigned short*)(ws + 48 * MB);   // 4 MB
  unsigned short* xb = (unsigned short*)(ws + 52 * MB);   // 4 MB
  unsigned short* Aeg = (unsigned short*)(ws + 56 * MB);  // 32 MB [gate -> out]
  unsigned short* pacc = (unsigned short*)(ws);           // 32 MB overlay (rb+eb dead)
  float* tau = (float*)(ws + 88 * MB);
  float* stat_s = (float*)(ws + 88 * MB + 1 * 65536);
  float* stat_q = (float*)(ws + 88 * MB + 2 * 65536);
  float* es_part = (float*)(ws + 88 * MB + 3 * 65536);    // 256 KB
  float* em_part = (float*)(ws + 88 * MB + 7 * 65536);    // 256 KB
  float* scale2 = (float*)(ws + 88 * MB + 11 * 65536);    // 16 KB
  if (ws_size < 88 * MB + 12 * 65536) return;
  float* outp = (float*)d_out;

  k_prep<<<22528, 256, 0, stream>>>(emb, w_read, h, x, w_write, eb, rb, hb, xb, wbT);
  k_stats<<<dim3(MDIM / 64, 8), 256, 0, stream>>>(hb, eb, stat_s, stat_q);
  k_tau<<<MDIM / 256, 256, 0, stream>>>(stat_s, stat_q, tau_off, tau);
  k_gate<<<256, 512, 0, stream>>>(hb, eb, xb, rb, tau, Aeg, es_part, em_part);
  k_scale<<<MDIM / 256, 256, 0, stream>>>(es_part, em_part, scale2);
  k_out<<<256, 512, 0, stream>>>(Aeg, wbT, pacc);
  k_finish<<<(MDIM * DDIM / 4) / 256, 256, 0, stream>>>(pacc, scale2, outp);
}

// Round 11
// 236.571 us; speedup vs baseline: 1.0402x; 1.0007x over previous
//
#include <hip/hip_runtime.h>

// DAWN_14886356647950: fused gated sparse read-write (B=2,S=1024,D=1024,N=8192,NC=8)
// R10: R9 (k_sc+k_xr fused, eg in 64 packed VGPRs) with the spill fixed:
// k_gate uses __launch_bounds__(512,1) -> 256-VGPR budget (LDS 137KB already
// caps occupancy at 1 block/CU, so the old ",2" bound only forced scratch
// spill of eg_pk: WRITE_SIZE 108MB vs 33MB expected). Everything else = R9/R7.

#define MDIM 2048
#define DDIM 1024
#define NDIM 8192

typedef __attribute__((ext_vector_type(8))) __bf16 bf16x8;
typedef __attribute__((ext_vector_type(4))) float f32x4;

static __device__ __forceinline__ unsigned short f2b(float f) {
  unsigned u = __float_as_uint(f);
  u = (u + 0x7FFFu + ((u >> 16) & 1u)) >> 16;  // RTNE
  return (unsigned short)u;
}
static __device__ __forceinline__ float b2f(unsigned short s) {
  return __uint_as_float(((unsigned)s) << 16);
}

#define LDSF(off) (*(const bf16x8*)(lds + (off)))
#define MFMA_BF16 __builtin_amdgcn_mfma_f32_16x16x32_bf16

#define GLOAD_LDS(gp, lp)                                                              \
  __builtin_amdgcn_global_load_lds(                                                    \
      (const __attribute__((address_space(1))) unsigned int*)(const void*)(gp),        \
      (__attribute__((address_space(3))) unsigned int*)(void*)(lp), 16, 0, 0)

// Stage one 128x64 half-tile (16KB); LDS dest linear (wave-uniform base + lane*16B),
// swizzle via permuted per-lane GLOBAL source column (involution with read-side XOR).
static __device__ __forceinline__ void stage_half(const unsigned short* __restrict__ src,
                                                  int ld, int row0, int k0,
                                                  char* lds, int lds_off, int w, int l) {
  const int rsub = l >> 3;
  const int col = k0 + 8 * ((l & 7) ^ rsub);
#pragma unroll
  for (int j = 0; j < 2; ++j) {
    const unsigned short* g =
        src + (size_t)(row0 + w * 8 + j * 64 + rsub) * (size_t)ld + col;
    GLOAD_LDS(g, lds + lds_off + j * 8192 + w * 1024);
  }
}

static __device__ __forceinline__ void stage4(const unsigned short* __restrict__ asrc,
                                              const unsigned short* __restrict__ bsrc,
                                              int ld, int m0, int n0, int k0,
                                              char* lds, int buf, int w, int l) {
  stage_half(asrc, ld, m0,       k0, lds, buf,         w, l);
  stage_half(asrc, ld, m0 + 128, k0, lds, buf + 16384, w, l);
  stage_half(bsrc, ld, n0,       k0, lds, buf + 32768, w, l);
  stage_half(bsrc, ld, n0 + 128, k0, lds, buf + 49152, w, l);
}

// 256x256 x K=1024 (16 tiles) NT-GEMM, 8 waves (2M x 4N), per-wave 128x64.
// 2-phase: per tile {stage t+1 -> buf^1 ; read frags of t ; lgkm0 ; 64 MFMA ;
// vmcnt(0) ; barrier}.
static __device__ __forceinline__ void gemm256(const unsigned short* __restrict__ asrc,
                                               const unsigned short* __restrict__ bsrc,
                                               int ld, int m0, int n0, int kbase,
                                               char* lds, f32x4 (&acc)[8][4],
                                               int w, int l, int wr, int wc) {
  const int lrow = l & 15, lk = l >> 4;
  const int axor = (l & 7) << 4;
  const int kx0 = (lk << 4) ^ axor;        // ks=0 swizzled k-byte
  const int kx1 = (64 | (lk << 4)) ^ axor; // ks=1
  const int arow_off = lrow * 128;
  const int brow_off = ((wc & 1) * 64 + lrow) * 128;

  stage4(asrc, bsrc, ld, m0, n0, kbase, lds, 0, w, l);
  asm volatile("s_waitcnt vmcnt(0)" ::: "memory");
  __builtin_amdgcn_s_barrier();

#pragma unroll 1
  for (int t = 0; t < 16; ++t) {
    const int buf = (t & 1) * 65536;
    const int nbuf = 65536 - buf;
    if (t < 15) stage4(asrc, bsrc, ld, m0, n0, kbase + (t + 1) * 64, lds, nbuf, w, l);

    const int ab = buf + wr * 16384;
    const int bb = buf + 32768 + (wc >> 1) * 16384;
    bf16x8 aLO[4][2], aHI[4][2], bLO[2][2], bHI[2][2];
#pragma unroll
    for (int m = 0; m < 4; ++m) {
      aLO[m][0] = LDSF(ab + arow_off + m * 2048 + kx0);
      aLO[m][1] = LDSF(ab + arow_off + m * 2048 + kx1);
    }
#pragma unroll
    for (int n = 0; n < 2; ++n) {
      bLO[n][0] = LDSF(bb + brow_off + n * 2048 + kx0);
      bLO[n][1] = LDSF(bb + brow_off + n * 2048 + kx1);
      bHI[n][0] = LDSF(bb + brow_off + (n + 2) * 2048 + kx0);
      bHI[n][1] = LDSF(bb + brow_off + (n + 2) * 2048 + kx1);
    }
    asm volatile("s_waitcnt lgkmcnt(0)" ::: "memory");
    __builtin_amdgcn_s_setprio(1);
#pragma unroll
    for (int ks = 0; ks < 2; ++ks)
#pragma unroll
      for (int n = 0; n < 2; ++n)
#pragma unroll
        for (int m = 0; m < 4; ++m)
          acc[m][n] = MFMA_BF16(aLO[m][ks], bLO[n][ks], acc[m][n], 0, 0, 0);
    __builtin_amdgcn_s_setprio(0);
#pragma unroll
    for (int m = 0; m < 4; ++m) {
      aHI[m][0] = LDSF(ab + arow_off + (m + 4) * 2048 + kx0);
      aHI[m][1] = LDSF(ab + arow_off + (m + 4) * 2048 + kx1);
    }
    __builtin_amdgcn_s_setprio(1);
#pragma unroll
    for (int ks = 0; ks < 2; ++ks)
#pragma unroll
      for (int n = 0; n < 2; ++n)
#pragma unroll
        for (int m = 0; m < 4; ++m)
          acc[m][n + 2] = MFMA_BF16(aLO[m][ks], bHI[n][ks], acc[m][n + 2], 0, 0, 0);
    __builtin_amdgcn_s_setprio(0);
    asm volatile("s_waitcnt lgkmcnt(0)" ::: "memory");
    __builtin_amdgcn_s_setprio(1);
#pragma unroll
    for (int ks = 0; ks < 2; ++ks)
#pragma unroll
      for (int n = 0; n < 2; ++n)
#pragma unroll
        for (int m = 0; m < 4; ++m)
          acc[m + 4][n + 2] = MFMA_BF16(aHI[m][ks], bHI[n][ks], acc[m + 4][n + 2], 0, 0, 0);
#pragma unroll
    for (int ks = 0; ks < 2; ++ks)
#pragma unroll
      for (int n = 0; n < 2; ++n)
#pragma unroll
        for (int m = 0; m < 4; ++m)
          acc[m + 4][n] = MFMA_BF16(aHI[m][ks], bLO[n][ks], acc[m + 4][n], 0, 0, 0);
    __builtin_amdgcn_s_setprio(0);
    asm volatile("s_waitcnt vmcnt(0)" ::: "memory");  // t+1 fully staged
    __builtin_amdgcn_s_barrier();
  }
}

// ==================== fused prep (single dispatch) ====================
// [0,2048): w_write transpose; [2048,10240): emb norm; [10240,22528): casts.

__global__ __launch_bounds__(256) void k_prep(const float* __restrict__ emb,
                                              const float* __restrict__ w_read,
                                              const float* __restrict__ h,
                                              const float* __restrict__ x,
                                              const float* __restrict__ w_write,
                                              unsigned short* __restrict__ eb,
                                              unsigned short* __restrict__ rb,
                                              unsigned short* __restrict__ hb,
                                              unsigned short* __restrict__ xb,
                                              unsigned short* __restrict__ wbT) {
  const int b = blockIdx.x, t = threadIdx.x;
  if (b < 2048) {  // w_write transpose
    __shared__ float tsm[64][65];
    const int nb = b & 127, db = b >> 7;
    const int r = t >> 2, c4 = (t & 3) * 16;
#pragma unroll
    for (int j = 0; j < 4; ++j) {
      const float4 v = *(const float4*)&w_write[(size_t)(nb * 64 + r) * 1024 + db * 64 + c4 + 4 * j];
      tsm[r][c4 + 4 * j + 0] = v.x;
      tsm[r][c4 + 4 * j + 1] = v.y;
      tsm[r][c4 + 4 * j + 2] = v.z;
      tsm[r][c4 + 4 * j + 3] = v.w;
    }
    __syncthreads();
    const int dr = t >> 2, nc0 = (t & 3) * 16;
    unsigned pk[8];
#pragma unroll
    for (int j = 0; j < 8; ++j) {
      const unsigned lo = f2b(tsm[nc0 + 2 * j][dr]);
      const unsigned hi = f2b(tsm[nc0 + 2 * j + 1][dr]);
      pk[j] = lo | (hi << 16);
    }
    uint4* dst = (uint4*)(wbT + (size_t)(db * 64 + dr) * 8192 + nb * 64 + nc0);
    uint4 w0, w1;
    w0.x = pk[0]; w0.y = pk[1]; w0.z = pk[2]; w0.w = pk[3];
    w1.x = pk[4]; w1.y = pk[5]; w1.z = pk[6]; w1.w = pk[7];
    dst[0] = w0;
    dst[1] = w1;
  } else if (b < 10240) {  // emb norm
    const int n = b - 2048;
    const float4 v = ((const float4*)(emb + (size_t)n * 1024))[t];
    float ss = v.x * v.x + v.y * v.y + v.z * v.z + v.w * v.w;
#pragma unroll
    for (int off = 1; off < 64; off <<= 1) ss += __shfl_xor(ss, off, 64);
    __shared__ float wsum[4];
    if ((t & 63) == 0) wsum[t >> 6] = ss;
    __syncthreads();
    const float denom = sqrtf(wsum[0] + wsum[1] + wsum[2] + wsum[3]) + 1e-8f;
    ushort4 o;
    o.x = f2b(v.x / denom);
    o.y = f2b(v.y / denom);
    o.z = f2b(v.z / denom);
    o.w = f2b(v.w / denom);
    ((ushort4*)(eb + (size_t)n * 1024))[t] = o;
  } else {  // casts
    const float* src;
    unsigned short* dst;
    int i;
    if (b < 18432) { src = w_read; dst = rb; i = (b - 10240) * 256 + t; }
    else if (b < 20480) { src = h; dst = hb; i = (b - 18432) * 256 + t; }
    else { src = x; dst = xb; i = (b - 20480) * 256 + t; }
    const float4 v = ((const float4*)src)[i];
    ushort4 o;
    o.x = f2b(v.x);
    o.y = f2b(v.y);
    o.z = f2b(v.z);
    o.w = f2b(v.w);
    ((ushort4*)dst)[i] = o;
  }
}

// ==================== stats (64x128 tiles, full-GPU grid) ====================

template <int TROWS>
static __device__ __forceinline__ void stage_tile(const unsigned short* __restrict__ src,
                                                  int row0, int k0, int ld,
                                                  unsigned short* lds, int wave, int lane) {
  const int rsub = lane >> 3;
  const int csub = (lane & 7) << 3;
#pragma unroll
  for (int q = 0; q < TROWS / 32; ++q) {
    const int p = q * 4 + wave;
    const unsigned short* g =
        src + (size_t)(row0 + p * 8 + rsub) * (size_t)ld + (size_t)(k0 + csub);
    GLOAD_LDS(g, lds + p * 512);
  }
}

__global__ __launch_bounds__(256, 2) void k_stats(const unsigned short* __restrict__ hb,
                                                  const unsigned short* __restrict__ eb,
                                                  float* __restrict__ stat_s,
                                                  float* __restrict__ stat_q) {
  __shared__ unsigned short a_sm[64 * 64];
  __shared__ unsigned short b_sm[128 * 64];
  __shared__ float red_s[2][64];
  __shared__ float red_q[2][64];
  const int t = threadIdx.x;
  const int wave = t >> 6, lane = t & 63;
  const int wr = wave >> 1, wc = wave & 1;
  const int m0 = blockIdx.x * 64, n0 = blockIdx.y * 128;
  const int arow = lane & 15;
  const int kcol = (lane >> 4) << 3;
  f32x4 acc[2][4];
#pragma unroll
  for (int m = 0; m < 2; ++m)
#pragma unroll
    for (int n = 0; n < 4; ++n) acc[m][n] = (f32x4)0.0f;
  for (int k0 = 0; k0 < 1024; k0 += 64) {
    stage_tile<64>(hb, m0, k0, 1024, a_sm, wave, lane);
    stage_tile<128>(eb, n0, k0, 1024, b_sm, wave, lane);
    asm volatile("s_waitcnt vmcnt(0)" ::: "memory");
    __syncthreads();
#pragma unroll
    for (int ks = 0; ks < 2; ++ks) {
      bf16x8 af[2], bfr[4];
#pragma unroll
      for (int m = 0; m < 2; ++m)
        af[m] = *(const bf16x8*)&a_sm[(wr * 32 + m * 16 + arow) * 64 + ks * 32 + kcol];
#pragma unroll
      for (int n = 0; n < 4; ++n)
        bfr[n] = *(const bf16x8*)&b_sm[(wc * 64 + n * 16 + arow) * 64 + ks * 32 + kcol];
#pragma unroll
      for (int m = 0; m < 2; ++m)
#pragma unroll
        for (int n = 0; n < 4; ++n)
          acc[m][n] = MFMA_BF16(af[m], bfr[n], acc[m][n], 0, 0, 0);
    }
    __syncthreads();
  }

  float s_r[2][4], q_r[2][4];
#pragma unroll
  for (int m = 0; m < 2; ++m)
#pragma unroll
    for (int i = 0; i < 4; ++i) { s_r[m][i] = 0.f; q_r[m][i] = 0.f; }
#pragma unroll
  for (int m = 0; m < 2; ++m)
#pragma unroll
    for (int n = 0; n < 4; ++n)
#pragma unroll
      for (int i = 0; i < 4; ++i) {
        const float scf = b2f(f2b(acc[m][n][i]));
        s_r[m][i] += scf;
        q_r[m][i] += b2f(f2b(scf * scf));
      }
#pragma unroll
  for (int m = 0; m < 2; ++m)
#pragma unroll
    for (int i = 0; i < 4; ++i) {
      float s = s_r[m][i], q = q_r[m][i];
      for (int off = 1; off < 16; off <<= 1) {
        s += __shfl_xor(s, off, 64);
        q += __shfl_xor(q, off, 64);
      }
      if ((lane & 15) == 0) {
        const int rloc = wr * 32 + m * 16 + (lane >> 4) * 4 + i;
        red_s[wc][rloc] = s;
        red_q[wc][rloc] = q;
      }
    }
  __syncthreads();
  if (t < 64) {
    stat_s[(size_t)(m0 + t) * 8 + blockIdx.y] = red_s[0][t] + red_s[1][t];
    stat_q[(size_t)(m0 + t) * 8 + blockIdx.y] = red_q[0][t] + red_q[1][t];
  }
}

__global__ void k_tau(const float* __restrict__ stat_s, const float* __restrict__ stat_q,
                      const float* __restrict__ tau_off, float* __restrict__ tau) {
  const int r = blockIdx.x * 256 + threadIdx.x;
  if (r >= MDIM) return;
  float S = 0.f, Q = 0.f;
#pragma unroll
  for (int j = 0; j < 8; ++j) {
    S += stat_s[(size_t)r * 8 + j];
    Q += stat_q[(size_t)r * 8 + j];
  }
  const float s_sum = S * 8.0f;
  const float sq_sum = Q * 8.0f;
  const float mean = s_sum * (1.0f / 8192.0f);
  const float var = __fsub_rn(sq_sum * (1.0f / 8192.0f), __fmul_rn(mean, mean));
  const float sd = __fadd_rn(__fsqrt_rn(var), 1e-8f);
  const float tv = __fadd_rn(mean, __fmul_rn(tau_off[r], sd));
  tau[r] = b2f(f2b(tv));
}

// ==================== k_gate: sc GEMM + gating (eg in regs) + xr GEMM + A ====================

__global__ __launch_bounds__(512, 1) void k_gate(const unsigned short* __restrict__ hb,
                                                 const unsigned short* __restrict__ eb,
                                                 const unsigned short* __restrict__ xb,
                                                 const unsigned short* __restrict__ rb,
                                                 const float* __restrict__ tau,
                                                 unsigned short* __restrict__ Aeg,
                                                 float* __restrict__ es_part,
                                                 float* __restrict__ em_part) {
  __shared__ __align__(16) char lds[131072];
  __shared__ float tau_sm[256];
  __shared__ float red_es[1024];
  __shared__ float red_em[1024];
  const int t = threadIdx.x, w = t >> 6, l = t & 63;
  const int wr = w >> 2, wc = w & 3;
  const int bid = blockIdx.x;
  const int swz = (bid & 7) * 32 + (bid >> 3);
  const int m0 = (swz >> 5) * 256, n0 = (swz & 31) * 256;
  const int lrow = l & 15, lk = l >> 4;

  f32x4 acc[8][4];
#pragma unroll
  for (int m = 0; m < 8; ++m)
#pragma unroll
    for (int n = 0; n < 4; ++n) acc[m][n] = (f32x4)0.0f;
  gemm256(hb, eb, 1024, m0, n0, 0, lds, acc, w, l, wr, wc);

  // --- gating: eg -> 64 packed VGPRs; es/em partials ---
  __syncthreads();
  if (t < 256) tau_sm[t] = tau[m0 + t];
  __syncthreads();
  unsigned eg_pk[8][4][2];
#pragma unroll
  for (int m = 0; m < 8; ++m) {
#pragma unroll
    for (int i = 0; i < 4; ++i) {
      const int rl = wr * 128 + m * 16 + lk * 4 + i;
      const float taub = tau_sm[rl];
      float es_v = 0.f, em_v = 0.f;
      unsigned p0 = 0, p1 = 0;
#pragma unroll
      for (int n = 0; n < 4; ++n) {
        const float scf = b2f(f2b(acc[m][n][i]));
        const float rawf = b2f(f2b(scf - taub));
        float gcf;
        if (rawf > 0.f) gcf = fminf(rawf, 10.0f);
        else gcf = b2f(f2b(1e-6f * expf(fmaxf(rawf, -10.0f))));
        const unsigned short egu = f2b(expf(gcf) - 1.0f);
        const float ef = b2f(egu);
        es_v += ef;
        em_v = fmaxf(em_v, ef);
        if (n < 2) p0 |= ((unsigned)egu) << (16 * n);
        else       p1 |= ((unsigned)egu) << (16 * (n - 2));
      }
      eg_pk[m][i][0] = p0;
      eg_pk[m][i][1] = p1;
      for (int off = 1; off < 16; off <<= 1) {
        es_v += __shfl_xor(es_v, off, 64);
        em_v = fmaxf(em_v, __shfl_xor(em_v, off, 64));
      }
      if (lrow == 0) {
        red_es[wc * 256 + rl] = es_v;
        red_em[wc * 256 + rl] = em_v;
      }
    }
  }
  __syncthreads();
  if (t < 256) {
    const float s = red_es[t] + red_es[256 + t] + red_es[512 + t] + red_es[768 + t];
    const float e = fmaxf(fmaxf(red_em[t], red_em[256 + t]),
                          fmaxf(red_em[512 + t], red_em[768 + t]));
    es_part[(size_t)(m0 + t) * 32 + (n0 >> 8)] = s;
    em_part[(size_t)(m0 + t) * 32 + (n0 >> 8)] = e;
  }

  // --- xr GEMM (lds reuse is safe: gemm prologue vmcnt+barrier republishes) ---
#pragma unroll
  for (int m = 0; m < 8; ++m)
#pragma unroll
    for (int n = 0; n < 4; ++n) acc[m][n] = (f32x4)0.0f;
  gemm256(xb, rb, 1024, m0, n0, 0, lds, acc, w, l, wr, wc);

  // --- A = bf16(eg * bf16(xr)), eg from registers ---
#pragma unroll
  for (int m = 0; m < 8; ++m)
#pragma unroll
    for (int n = 0; n < 4; ++n)
#pragma unroll
      for (int i = 0; i < 4; ++i) {
        const int rl = wr * 128 + m * 16 + lk * 4 + i;
        const unsigned short egu =
            (unsigned short)((eg_pk[m][i][n >> 1] >> (16 * (n & 1))) & 0xFFFFu);
        const float xrf = b2f(f2b(acc[m][n][i]));
        Aeg[(size_t)(m0 + rl) * NDIM + (size_t)(n0 + wc * 64 + n * 16 + lrow)] =
            f2b(b2f(egu) * xrf);
      }
}

// ==================== k_out: per-chunk GEMM -> bf16 partial ====================

__global__ __launch_bounds__(512, 2) void k_out(const unsigned short* __restrict__ A,
                                                const unsigned short* __restrict__ wbT,
                                                unsigned short* __restrict__ pacc) {
  __shared__ __align__(16) char lds[131072];
  const int t = threadIdx.x, w = t >> 6, l = t & 63;
  const int wr = w >> 2, wc = w & 3;
  const int bid = blockIdx.x;
  const int swz = (bid & 7) * 32 + (bid >> 3);
  const int bm = swz >> 5, chunk = (swz >> 2) & 7, bd = swz & 3;
  const int m0 = bm * 256, d0 = bd * 256;
  f32x4 acc[8][4];
#pragma unroll
  for (int m = 0; m < 8; ++m)
#pragma unroll
    for (int n = 0; n < 4; ++n) acc[m][n] = (f32x4)0.0f;
  gemm256(A, wbT, 8192, m0, d0, chunk * 1024, lds, acc, w, l, wr, wc);

  const int lrow = l & 15, lk = l >> 4;
#pragma unroll
  for (int m = 0; m < 8; ++m)
#pragma unroll
    for (int n = 0; n < 4; ++n)
#pragma unroll
      for (int i = 0; i < 4; ++i) {
        const int rl = wr * 128 + m * 16 + lk * 4 + i;
        pacc[((size_t)chunk * MDIM + (m0 + rl)) * DDIM +
             (size_t)(d0 + wc * 64 + n * 16 + lrow)] = f2b(acc[m][n][i]);
      }
}

// ==================== scales + finish ====================

__global__ void k_scale(const float* __restrict__ es_part, const float* __restrict__ em_part,
                        float* __restrict__ scale2) {
  const int r = blockIdx.x * 256 + threadIdx.x;
  if (r >= MDIM) return;
  float s = 0.f, m = 0.f;
#pragma unroll
  for (int j = 0; j < 32; ++j) {
    s += es_part[(size_t)r * 32 + j];
    m = fmaxf(m, em_part[(size_t)r * 32 + j]);
  }
  scale2[2 * r] = b2f(f2b(1.0f / (s + 1e-8f)));  // inv_es (bf16 value)
  scale2[2 * r + 1] = b2f(f2b(tanhf(m)));        // gs (bf16 value)
}

__global__ __launch_bounds__(256) void k_finish(const unsigned short* __restrict__ pacc,
                                                const float* __restrict__ scale2,
                                                float* __restrict__ outp) {
  const int t = blockIdx.x * 256 + threadIdx.x;
  const int r = t >> 8;
  const int d4 = (t & 255) * 4;
  float sx = 0.f, sy = 0.f, sz = 0.f, sw = 0.f;
#pragma unroll
  for (int c = 0; c < 8; ++c) {
    const ushort4 v = *(const ushort4*)(pacc + ((size_t)c * MDIM + r) * DDIM + d4);
    sx += b2f(v.x);
    sy += b2f(v.y);
    sz += b2f(v.z);
    sw += b2f(v.w);
  }
  const float inv = scale2[2 * r];
  const float gsv = scale2[2 * r + 1];
  float4 o;
  o.x = (sx * inv) * gsv;
  o.y = (sy * inv) * gsv;
  o.z = (sz * inv) * gsv;
  o.w = (sw * inv) * gsv;
  *(float4*)(outp + (size_t)r * DDIM + d4) = o;
}

// ==================== launch ====================

extern "C" void kernel_launch(void* const* d_in, const int* in_sizes, int n_in,
                              void* d_out, int out_size, void* d_ws, size_t ws_size,
                              hipStream_t stream) {
  const float* x = (const float*)d_in[0];
  const float* h = (const float*)d_in[1];
  const float* emb = (const float*)d_in[2];
  const float* tau_off = (const float*)d_in[3];
  const float* w_read = (const float*)d_in[4];
  const float* w_write = (const float*)d_in[5];

  char* ws = (char*)d_ws;
  const size_t MB = 1024 * 1024;
  unsigned short* rb = (unsigned short*)(ws);             // 16 MB [prep -> gate]
  unsigned short* eb = (unsigned short*)(ws + 16 * MB);   // 16 MB [prep -> gate]
  unsigned short* wbT = (unsigned short*)(ws + 32 * MB);  // 16 MB [prep -> out]
  unsigned short* hb = (unsigned short*)(ws + 48 * MB);   // 4 MB
  unsigned short* xb = (unsigned short*)(ws + 52 * MB);   // 4 MB
  unsigned short* Aeg = (unsigned short*)(ws + 56 * MB);  // 32 MB [gate -> out]
  unsigned short* pacc = (unsigned short*)(ws);           // 32 MB overlay (rb+eb dead)
  float* tau = (float*)(ws + 88 * MB);
  float* stat_s = (float*)(ws + 88 * MB + 1 * 65536);
  float* stat_q = (float*)(ws + 88 * MB + 2 * 65536);
  float* es_part = (float*)(ws + 88 * MB + 3 * 65536);    // 256 KB
  float* em_part = (float*)(ws + 88 * MB + 7 * 65536);    // 256 KB
  float* scale2 = (float*)(ws + 88 * MB + 11 * 65536);    // 16 KB
  if (ws_size < 88 * MB + 12 * 65536) return;
  float* outp = (float*)d_out;

  k_prep<<<22528, 256, 0, stream>>>(emb, w_read, h, x, w_write, eb, rb, hb, xb, wbT);
  k_stats<<<dim3(MDIM / 64, 8), 256, 0, stream>>>(hb, eb, stat_s, stat_q);
  k_tau<<<MDIM / 256, 256, 0, stream>>>(stat_s, stat_q, tau_off, tau);
  k_gate<<<256, 512, 0, stream>>>(hb, eb, xb, rb, tau, Aeg, es_part, em_part);
  k_scale<<<MDIM / 256, 256, 0, stream>>>(es_part, em_part, scale2);
  k_out<<<256, 512, 0, stream>>>(Aeg, wbT, pacc);
  k_finish<<<(MDIM * DDIM / 4) / 256, 256, 0, stream>>>(pacc, scale2, outp);
}

// Round 12
// 186.436 us; speedup vs baseline: 1.3199x; 1.2689x over previous
//
#include <hip/hip_runtime.h>

// DAWN_14886356647950: fused gated sparse read-write (B=2,S=1024,D=1024,N=8192,NC=8)
// R11: revert to R7 (best measured, 190.6us — fusion structurally infeasible:
// 512-thr block caps 256 regs/wave, acc(128 AGPR)+128 VGPR already full) +
// fold k_tau into k_sc prologue and k_scale into k_finish (2 fewer launches,
// bit-identical arithmetic). GEMM core: 2-phase 256^2, one barrier + one
// vmcnt(0) per K-tile (the measured plain-HIP plateau at this shape).

#define MDIM 2048
#define DDIM 1024
#define NDIM 8192

typedef __attribute__((ext_vector_type(8))) __bf16 bf16x8;
typedef __attribute__((ext_vector_type(4))) float f32x4;

static __device__ __forceinline__ unsigned short f2b(float f) {
  unsigned u = __float_as_uint(f);
  u = (u + 0x7FFFu + ((u >> 16) & 1u)) >> 16;  // RTNE
  return (unsigned short)u;
}
static __device__ __forceinline__ float b2f(unsigned short s) {
  return __uint_as_float(((unsigned)s) << 16);
}

#define LDSF(off) (*(const bf16x8*)(lds + (off)))
#define MFMA_BF16 __builtin_amdgcn_mfma_f32_16x16x32_bf16

#define GLOAD_LDS(gp, lp)                                                              \
  __builtin_amdgcn_global_load_lds(                                                    \
      (const __attribute__((address_space(1))) unsigned int*)(const void*)(gp),        \
      (__attribute__((address_space(3))) unsigned int*)(void*)(lp), 16, 0, 0)

// Stage one 128x64 half-tile (16KB); LDS dest linear (wave-uniform base + lane*16B),
// swizzle via permuted per-lane GLOBAL source column (involution with read-side XOR).
static __device__ __forceinline__ void stage_half(const unsigned short* __restrict__ src,
                                                  int ld, int row0, int k0,
                                                  char* lds, int lds_off, int w, int l) {
  const int rsub = l >> 3;
  const int col = k0 + 8 * ((l & 7) ^ rsub);
#pragma unroll
  for (int j = 0; j < 2; ++j) {
    const unsigned short* g =
        src + (size_t)(row0 + w * 8 + j * 64 + rsub) * (size_t)ld + col;
    GLOAD_LDS(g, lds + lds_off + j * 8192 + w * 1024);
  }
}

// Stage one full 256x64 K-tile (A0,A1,B0,B1) = 8 global_load_lds.
static __device__ __forceinline__ void stage4(const unsigned short* __restrict__ asrc,
                                              const unsigned short* __restrict__ bsrc,
                                              int ld, int m0, int n0, int k0,
                                              char* lds, int buf, int w, int l) {
  stage_half(asrc, ld, m0,       k0, lds, buf,         w, l);
  stage_half(asrc, ld, m0 + 128, k0, lds, buf + 16384, w, l);
  stage_half(bsrc, ld, n0,       k0, lds, buf + 32768, w, l);
  stage_half(bsrc, ld, n0 + 128, k0, lds, buf + 49152, w, l);
}

// 256x256 x K=1024 (16 tiles) NT-GEMM, 8 waves (2M x 4N), per-wave 128x64.
// 2-phase: per tile {stage t+1 -> buf^1 ; read frags of t ; lgkm0 ; 64 MFMA ;
// vmcnt(0) ; barrier}.
static __device__ __forceinline__ void gemm256(const unsigned short* __restrict__ asrc,
                                               const unsigned short* __restrict__ bsrc,
                                               int ld, int m0, int n0, int kbase,
                                               char* lds, f32x4 (&acc)[8][4],
                                               int w, int l, int wr, int wc) {
  const int lrow = l & 15, lk = l >> 4;
  const int axor = (l & 7) << 4;
  const int kx0 = (lk << 4) ^ axor;        // ks=0 swizzled k-byte
  const int kx1 = (64 | (lk << 4)) ^ axor; // ks=1
  const int arow_off = lrow * 128;
  const int brow_off = ((wc & 1) * 64 + lrow) * 128;

  stage4(asrc, bsrc, ld, m0, n0, kbase, lds, 0, w, l);
  asm volatile("s_waitcnt vmcnt(0)" ::: "memory");
  __builtin_amdgcn_s_barrier();

#pragma unroll 1
  for (int t = 0; t < 16; ++t) {
    const int buf = (t & 1) * 65536;
    const int nbuf = 65536 - buf;
    if (t < 15) stage4(asrc, bsrc, ld, m0, n0, kbase + (t + 1) * 64, lds, nbuf, w, l);

    const int ab = buf + wr * 16384;
    const int bb = buf + 32768 + (wc >> 1) * 16384;
    bf16x8 aLO[4][2], aHI[4][2], bLO[2][2], bHI[2][2];
#pragma unroll
    for (int m = 0; m < 4; ++m) {
      aLO[m][0] = LDSF(ab + arow_off + m * 2048 + kx0);
      aLO[m][1] = LDSF(ab + arow_off + m * 2048 + kx1);
    }
#pragma unroll
    for (int n = 0; n < 2; ++n) {
      bLO[n][0] = LDSF(bb + brow_off + n * 2048 + kx0);
      bLO[n][1] = LDSF(bb + brow_off + n * 2048 + kx1);
      bHI[n][0] = LDSF(bb + brow_off + (n + 2) * 2048 + kx0);
      bHI[n][1] = LDSF(bb + brow_off + (n + 2) * 2048 + kx1);
    }
    asm volatile("s_waitcnt lgkmcnt(0)" ::: "memory");
    __builtin_amdgcn_s_setprio(1);
#pragma unroll
    for (int ks = 0; ks < 2; ++ks)
#pragma unroll
      for (int n = 0; n < 2; ++n)
#pragma unroll
        for (int m = 0; m < 4; ++m)
          acc[m][n] = MFMA_BF16(aLO[m][ks], bLO[n][ks], acc[m][n], 0, 0, 0);
    __builtin_amdgcn_s_setprio(0);
#pragma unroll
    for (int m = 0; m < 4; ++m) {
      aHI[m][0] = LDSF(ab + arow_off + (m + 4) * 2048 + kx0);
      aHI[m][1] = LDSF(ab + arow_off + (m + 4) * 2048 + kx1);
    }
    __builtin_amdgcn_s_setprio(1);
#pragma unroll
    for (int ks = 0; ks < 2; ++ks)
#pragma unroll
      for (int n = 0; n < 2; ++n)
#pragma unroll
        for (int m = 0; m < 4; ++m)
          acc[m][n + 2] = MFMA_BF16(aLO[m][ks], bHI[n][ks], acc[m][n + 2], 0, 0, 0);
    __builtin_amdgcn_s_setprio(0);
    asm volatile("s_waitcnt lgkmcnt(0)" ::: "memory");
    __builtin_amdgcn_s_setprio(1);
#pragma unroll
    for (int ks = 0; ks < 2; ++ks)
#pragma unroll
      for (int n = 0; n < 2; ++n)
#pragma unroll
        for (int m = 0; m < 4; ++m)
          acc[m + 4][n + 2] = MFMA_BF16(aHI[m][ks], bHI[n][ks], acc[m + 4][n + 2], 0, 0, 0);
#pragma unroll
    for (int ks = 0; ks < 2; ++ks)
#pragma unroll
      for (int n = 0; n < 2; ++n)
#pragma unroll
        for (int m = 0; m < 4; ++m)
          acc[m + 4][n] = MFMA_BF16(aHI[m][ks], bLO[n][ks], acc[m + 4][n], 0, 0, 0);
    __builtin_amdgcn_s_setprio(0);
    asm volatile("s_waitcnt vmcnt(0)" ::: "memory");  // t+1 fully staged
    __builtin_amdgcn_s_barrier();
  }
}

// ==================== fused prep (single dispatch) ====================
// [0,2048): w_write transpose; [2048,10240): emb norm; [10240,22528): casts.

__global__ __launch_bounds__(256) void k_prep(const float* __restrict__ emb,
                                              const float* __restrict__ w_read,
                                              const float* __restrict__ h,
                                              const float* __restrict__ x,
                                              const float* __restrict__ w_write,
                                              unsigned short* __restrict__ eb,
                                              unsigned short* __restrict__ rb,
                                              unsigned short* __restrict__ hb,
                                              unsigned short* __restrict__ xb,
                                              unsigned short* __restrict__ wbT) {
  const int b = blockIdx.x, t = threadIdx.x;
  if (b < 2048) {  // w_write transpose
    __shared__ float tsm[64][65];
    const int nb = b & 127, db = b >> 7;
    const int r = t >> 2, c4 = (t & 3) * 16;
#pragma unroll
    for (int j = 0; j < 4; ++j) {
      const float4 v = *(const float4*)&w_write[(size_t)(nb * 64 + r) * 1024 + db * 64 + c4 + 4 * j];
      tsm[r][c4 + 4 * j + 0] = v.x;
      tsm[r][c4 + 4 * j + 1] = v.y;
      tsm[r][c4 + 4 * j + 2] = v.z;
      tsm[r][c4 + 4 * j + 3] = v.w;
    }
    __syncthreads();
    const int dr = t >> 2, nc0 = (t & 3) * 16;
    unsigned pk[8];
#pragma unroll
    for (int j = 0; j < 8; ++j) {
      const unsigned lo = f2b(tsm[nc0 + 2 * j][dr]);
      const unsigned hi = f2b(tsm[nc0 + 2 * j + 1][dr]);
      pk[j] = lo | (hi << 16);
    }
    uint4* dst = (uint4*)(wbT + (size_t)(db * 64 + dr) * 8192 + nb * 64 + nc0);
    uint4 w0, w1;
    w0.x = pk[0]; w0.y = pk[1]; w0.z = pk[2]; w0.w = pk[3];
    w1.x = pk[4]; w1.y = pk[5]; w1.z = pk[6]; w1.w = pk[7];
    dst[0] = w0;
    dst[1] = w1;
  } else if (b < 10240) {  // emb norm
    const int n = b - 2048;
    const float4 v = ((const float4*)(emb + (size_t)n * 1024))[t];
    float ss = v.x * v.x + v.y * v.y + v.z * v.z + v.w * v.w;
#pragma unroll
    for (int off = 1; off < 64; off <<= 1) ss += __shfl_xor(ss, off, 64);
    __shared__ float wsum[4];
    if ((t & 63) == 0) wsum[t >> 6] = ss;
    __syncthreads();
    const float denom = sqrtf(wsum[0] + wsum[1] + wsum[2] + wsum[3]) + 1e-8f;
    ushort4 o;
    o.x = f2b(v.x / denom);
    o.y = f2b(v.y / denom);
    o.z = f2b(v.z / denom);
    o.w = f2b(v.w / denom);
    ((ushort4*)(eb + (size_t)n * 1024))[t] = o;
  } else {  // casts
    const float* src;
    unsigned short* dst;
    int i;
    if (b < 18432) { src = w_read; dst = rb; i = (b - 10240) * 256 + t; }
    else if (b < 20480) { src = h; dst = hb; i = (b - 18432) * 256 + t; }
    else { src = x; dst = xb; i = (b - 20480) * 256 + t; }
    const float4 v = ((const float4*)src)[i];
    ushort4 o;
    o.x = f2b(v.x);
    o.y = f2b(v.y);
    o.z = f2b(v.z);
    o.w = f2b(v.w);
    ((ushort4*)dst)[i] = o;
  }
}

// ==================== stats (64x128 tiles, full-GPU grid) ====================

template <int TROWS>
static __device__ __forceinline__ void stage_tile(const unsigned short* __restrict__ src,
                                                  int row0, int k0, int ld,
                                                  unsigned short* lds, int wave, int lane) {
  const int rsub = lane >> 3;
  const int csub = (lane & 7) << 3;
#pragma unroll
  for (int q = 0; q < TROWS / 32; ++q) {
    const int p = q * 4 + wave;
    const unsigned short* g =
        src + (size_t)(row0 + p * 8 + rsub) * (size_t)ld + (size_t)(k0 + csub);
    GLOAD_LDS(g, lds + p * 512);
  }
}

__global__ __launch_bounds__(256, 2) void k_stats(const unsigned short* __restrict__ hb,
                                                  const unsigned short* __restrict__ eb,
                                                  float* __restrict__ stat_s,
                                                  float* __restrict__ stat_q) {
  __shared__ unsigned short a_sm[64 * 64];
  __shared__ unsigned short b_sm[128 * 64];
  __shared__ float red_s[2][64];
  __shared__ float red_q[2][64];
  const int t = threadIdx.x;
  const int wave = t >> 6, lane = t & 63;
  const int wr = wave >> 1, wc = wave & 1;  // 2M x 2N waves; per-wave 32x64
  const int m0 = blockIdx.x * 64, n0 = blockIdx.y * 128;
  const int arow = lane & 15;
  const int kcol = (lane >> 4) << 3;
  f32x4 acc[2][4];
#pragma unroll
  for (int m = 0; m < 2; ++m)
#pragma unroll
    for (int n = 0; n < 4; ++n) acc[m][n] = (f32x4)0.0f;
  for (int k0 = 0; k0 < 1024; k0 += 64) {
    stage_tile<64>(hb, m0, k0, 1024, a_sm, wave, lane);
    stage_tile<128>(eb, n0, k0, 1024, b_sm, wave, lane);
    asm volatile("s_waitcnt vmcnt(0)" ::: "memory");
    __syncthreads();
#pragma unroll
    for (int ks = 0; ks < 2; ++ks) {
      bf16x8 af[2], bfr[4];
#pragma unroll
      for (int m = 0; m < 2; ++m)
        af[m] = *(const bf16x8*)&a_sm[(wr * 32 + m * 16 + arow) * 64 + ks * 32 + kcol];
#pragma unroll
      for (int n = 0; n < 4; ++n)
        bfr[n] = *(const bf16x8*)&b_sm[(wc * 64 + n * 16 + arow) * 64 + ks * 32 + kcol];
#pragma unroll
      for (int m = 0; m < 2; ++m)
#pragma unroll
        for (int n = 0; n < 4; ++n)
          acc[m][n] = MFMA_BF16(af[m], bfr[n], acc[m][n], 0, 0, 0);
    }
    __syncthreads();
  }

  float s_r[2][4], q_r[2][4];
#pragma unroll
  for (int m = 0; m < 2; ++m)
#pragma unroll
    for (int i = 0; i < 4; ++i) { s_r[m][i] = 0.f; q_r[m][i] = 0.f; }
#pragma unroll
  for (int m = 0; m < 2; ++m)
#pragma unroll
    for (int n = 0; n < 4; ++n)
#pragma unroll
      for (int i = 0; i < 4; ++i) {
        const float scf = b2f(f2b(acc[m][n][i]));
        s_r[m][i] += scf;
        q_r[m][i] += b2f(f2b(scf * scf));
      }
#pragma unroll
  for (int m = 0; m < 2; ++m)
#pragma unroll
    for (int i = 0; i < 4; ++i) {
      float s = s_r[m][i], q = q_r[m][i];
      for (int off = 1; off < 16; off <<= 1) {
        s += __shfl_xor(s, off, 64);
        q += __shfl_xor(q, off, 64);
      }
      if ((lane & 15) == 0) {
        const int rloc = wr * 32 + m * 16 + (lane >> 4) * 4 + i;
        red_s[wc][rloc] = s;
        red_q[wc][rloc] = q;
      }
    }
  __syncthreads();
  if (t < 64) {
    stat_s[(size_t)(m0 + t) * 8 + blockIdx.y] = red_s[0][t] + red_s[1][t];
    stat_q[(size_t)(m0 + t) * 8 + blockIdx.y] = red_q[0][t] + red_q[1][t];
  }
}

// ==================== k_sc: sc GEMM + inline tau + gating -> eg, es/em ====================

__global__ __launch_bounds__(512, 2) void k_sc(const unsigned short* __restrict__ hb,
                                               const unsigned short* __restrict__ eb,
                                               const float* __restrict__ stat_s,
                                               const float* __restrict__ stat_q,
                                               const float* __restrict__ tau_off,
                                               unsigned short* __restrict__ Aeg,
                                               float* __restrict__ es_part,
                                               float* __restrict__ em_part) {
  __shared__ __align__(16) char lds[131072];
  const int t = threadIdx.x, w = t >> 6, l = t & 63;
  const int wr = w >> 2, wc = w & 3;
  const int bid = blockIdx.x;
  const int swz = (bid & 7) * 32 + (bid >> 3);
  const int m0 = (swz >> 5) * 256, n0 = (swz & 31) * 256;
  f32x4 acc[8][4];
#pragma unroll
  for (int m = 0; m < 8; ++m)
#pragma unroll
    for (int n = 0; n < 4; ++n) acc[m][n] = (f32x4)0.0f;
  gemm256(hb, eb, 1024, m0, n0, 0, lds, acc, w, l, wr, wc);

  __syncthreads();
  float* tau_sm = (float*)lds;
  float* red_es = (float*)(lds + 1024);
  float* red_em = (float*)(lds + 1024 + 4096);
  if (t < 256) {
    // inline k_tau (bit-identical op order to the former k_tau kernel)
    const int r = m0 + t;
    float S = 0.f, Q = 0.f;
#pragma unroll
    for (int j = 0; j < 8; ++j) {
      S += stat_s[(size_t)r * 8 + j];
      Q += stat_q[(size_t)r * 8 + j];
    }
    const float s_sum = S * 8.0f;
    const float sq_sum = Q * 8.0f;
    const float mean = s_sum * (1.0f / 8192.0f);
    const float var = __fsub_rn(sq_sum * (1.0f / 8192.0f), __fmul_rn(mean, mean));
    const float sd = __fadd_rn(__fsqrt_rn(var), 1e-8f);
    const float tv = __fadd_rn(mean, __fmul_rn(tau_off[r], sd));
    tau_sm[t] = b2f(f2b(tv));
  }
  __syncthreads();
  const int lrow = l & 15, lk = l >> 4;
#pragma unroll
  for (int m = 0; m < 8; ++m) {
#pragma unroll
    for (int i = 0; i < 4; ++i) {
      const int rl = wr * 128 + m * 16 + lk * 4 + i;
      const float taub = tau_sm[rl];
      float es_v = 0.f, em_v = 0.f;
#pragma unroll
      for (int n = 0; n < 4; ++n) {
        const float scf = b2f(f2b(acc[m][n][i]));
        const float rawf = b2f(f2b(scf - taub));
        float gcf;
        if (rawf > 0.f) gcf = fminf(rawf, 10.0f);
        else gcf = b2f(f2b(1e-6f * expf(fmaxf(rawf, -10.0f))));
        const unsigned short egu = f2b(expf(gcf) - 1.0f);
        const float ef = b2f(egu);
        es_v += ef;
        em_v = fmaxf(em_v, ef);
        Aeg[(size_t)(m0 + rl) * NDIM + (size_t)(n0 + wc * 64 + n * 16 + lrow)] = egu;
      }
      for (int off = 1; off < 16; off <<= 1) {
        es_v += __shfl_xor(es_v, off, 64);
        em_v = fmaxf(em_v, __shfl_xor(em_v, off, 64));
      }
      if (lrow == 0) {
        red_es[wc * 256 + rl] = es_v;
        red_em[wc * 256 + rl] = em_v;
      }
    }
  }
  __syncthreads();
  if (t < 256) {
    const float s = red_es[t] + red_es[256 + t] + red_es[512 + t] + red_es[768 + t];
    const float e = fmaxf(fmaxf(red_em[t], red_em[256 + t]),
                          fmaxf(red_em[512 + t], red_em[768 + t]));
    es_part[(size_t)(m0 + t) * 32 + (n0 >> 8)] = s;
    em_part[(size_t)(m0 + t) * 32 + (n0 >> 8)] = e;
  }
}

// ==================== k_xr: xr GEMM, A = bf16(eg * xr) in place ====================

__global__ __launch_bounds__(512, 2) void k_xr(const unsigned short* __restrict__ xb,
                                               const unsigned short* __restrict__ rb,
                                               unsigned short* __restrict__ Aeg) {
  __shared__ __align__(16) char lds[131072];
  const int t = threadIdx.x, w = t >> 6, l = t & 63;
  const int wr = w >> 2, wc = w & 3;
  const int bid = blockIdx.x;
  const int swz = (bid & 7) * 32 + (bid >> 3);
  const int m0 = (swz >> 5) * 256, n0 = (swz & 31) * 256;
  f32x4 acc[8][4];
#pragma unroll
  for (int m = 0; m < 8; ++m)
#pragma unroll
    for (int n = 0; n < 4; ++n) acc[m][n] = (f32x4)0.0f;
  gemm256(xb, rb, 1024, m0, n0, 0, lds, acc, w, l, wr, wc);

  const int lrow = l & 15, lk = l >> 4;
#pragma unroll
  for (int m = 0; m < 8; ++m)
#pragma unroll
    for (int n = 0; n < 4; ++n)
#pragma unroll
      for (int i = 0; i < 4; ++i) {
        const int rl = wr * 128 + m * 16 + lk * 4 + i;
        const size_t idx =
            (size_t)(m0 + rl) * NDIM + (size_t)(n0 + wc * 64 + n * 16 + lrow);
        const unsigned short egu = Aeg[idx];
        const float xrf = b2f(f2b(acc[m][n][i]));
        Aeg[idx] = f2b(b2f(egu) * xrf);
      }
}

// ==================== k_out: per-chunk GEMM -> bf16 partial ====================

__global__ __launch_bounds__(512, 2) void k_out(const unsigned short* __restrict__ A,
                                                const unsigned short* __restrict__ wbT,
                                                unsigned short* __restrict__ pacc) {
  __shared__ __align__(16) char lds[131072];
  const int t = threadIdx.x, w = t >> 6, l = t & 63;
  const int wr = w >> 2, wc = w & 3;
  const int bid = blockIdx.x;
  const int swz = (bid & 7) * 32 + (bid >> 3);
  const int bm = swz >> 5, chunk = (swz >> 2) & 7, bd = swz & 3;
  const int m0 = bm * 256, d0 = bd * 256;
  f32x4 acc[8][4];
#pragma unroll
  for (int m = 0; m < 8; ++m)
#pragma unroll
    for (int n = 0; n < 4; ++n) acc[m][n] = (f32x4)0.0f;
  gemm256(A, wbT, 8192, m0, d0, chunk * 1024, lds, acc, w, l, wr, wc);

  const int lrow = l & 15, lk = l >> 4;
#pragma unroll
  for (int m = 0; m < 8; ++m)
#pragma unroll
    for (int n = 0; n < 4; ++n)
#pragma unroll
      for (int i = 0; i < 4; ++i) {
        const int rl = wr * 128 + m * 16 + lk * 4 + i;
        pacc[((size_t)chunk * MDIM + (m0 + rl)) * DDIM +
             (size_t)(d0 + wc * 64 + n * 16 + lrow)] = f2b(acc[m][n][i]);
      }
}

// ==================== finish (inline k_scale) ====================

__global__ __launch_bounds__(256) void k_finish(const unsigned short* __restrict__ pacc,
                                                const float* __restrict__ es_part,
                                                const float* __restrict__ em_part,
                                                float* __restrict__ outp) {
  const int t = blockIdx.x * 256 + threadIdx.x;
  const int r = t >> 8;
  const int d4 = (t & 255) * 4;
  // inline k_scale (bit-identical op order); same-address loads broadcast.
  float s = 0.f, m = 0.f;
#pragma unroll
  for (int j = 0; j < 32; ++j) {
    s += es_part[(size_t)r * 32 + j];
    m = fmaxf(m, em_part[(size_t)r * 32 + j]);
  }
  const float inv = b2f(f2b(1.0f / (s + 1e-8f)));
  const float gsv = b2f(f2b(tanhf(m)));
  float sx = 0.f, sy = 0.f, sz = 0.f, sw = 0.f;
#pragma unroll
  for (int c = 0; c < 8; ++c) {
    const ushort4 v = *(const ushort4*)(pacc + ((size_t)c * MDIM + r) * DDIM + d4);
    sx += b2f(v.x);
    sy += b2f(v.y);
    sz += b2f(v.z);
    sw += b2f(v.w);
  }
  float4 o;
  o.x = (sx * inv) * gsv;
  o.y = (sy * inv) * gsv;
  o.z = (sz * inv) * gsv;
  o.w = (sw * inv) * gsv;
  *(float4*)(outp + (size_t)r * DDIM + d4) = o;
}

// ==================== launch ====================

extern "C" void kernel_launch(void* const* d_in, const int* in_sizes, int n_in,
                              void* d_out, int out_size, void* d_ws, size_t ws_size,
                              hipStream_t stream) {
  const float* x = (const float*)d_in[0];
  const float* h = (const float*)d_in[1];
  const float* emb = (const float*)d_in[2];
  const float* tau_off = (const float*)d_in[3];
  const float* w_read = (const float*)d_in[4];
  const float* w_write = (const float*)d_in[5];

  char* ws = (char*)d_ws;
  const size_t MB = 1024 * 1024;
  unsigned short* rb = (unsigned short*)(ws);             // 16 MB [prep -> xr]
  unsigned short* eb = (unsigned short*)(ws + 16 * MB);   // 16 MB [prep -> sc]
  unsigned short* wbT = (unsigned short*)(ws + 32 * MB);  // 16 MB [prep -> out]
  unsigned short* hb = (unsigned short*)(ws + 48 * MB);   // 4 MB
  unsigned short* xb = (unsigned short*)(ws + 52 * MB);   // 4 MB
  unsigned short* Aeg = (unsigned short*)(ws + 56 * MB);  // 32 MB [sc -> xr -> out]
  unsigned short* pacc = (unsigned short*)(ws);           // 32 MB overlay (rb+eb dead)
  float* stat_s = (float*)(ws + 88 * MB + 1 * 65536);
  float* stat_q = (float*)(ws + 88 * MB + 2 * 65536);
  float* es_part = (float*)(ws + 88 * MB + 3 * 65536);    // 256 KB
  float* em_part = (float*)(ws + 88 * MB + 7 * 65536);    // 256 KB
  if (ws_size < 88 * MB + 11 * 65536) return;
  float* outp = (float*)d_out;

  k_prep<<<22528, 256, 0, stream>>>(emb, w_read, h, x, w_write, eb, rb, hb, xb, wbT);
  k_stats<<<dim3(MDIM / 64, 8), 256, 0, stream>>>(hb, eb, stat_s, stat_q);
  k_sc<<<256, 512, 0, stream>>>(hb, eb, stat_s, stat_q, tau_off, Aeg, es_part, em_part);
  k_xr<<<256, 512, 0, stream>>>(xb, rb, Aeg);
  k_out<<<256, 512, 0, stream>>>(Aeg, wbT, pacc);
  k_finish<<<(MDIM * DDIM / 4) / 256, 256, 0, stream>>>(pacc, es_part, em_part, outp);
}